// Round 5
// baseline (50582.504 us; speedup 1.0000x reference)
//
#include <hip/hip_runtime.h>

// Problem constants
constexpr int Bn = 8, Tn = 16, Nn = 512, Cn = 64, Hn = 64, En = 16384, Ln = 2;
constexpr int NC = Nn * Cn;           // 32768
constexpr int MROWS = Bn * Nn;        // 4096

// ---------------- workspace layout (in floats) ----------------
constexpr size_t OFF_DEG  = 0;                            // 512
constexpr size_t OFF_DINV = 512;                          // 512
constexpr size_t OFF_L1D  = 1024;                         // 512*512
constexpr size_t OFF_L2D  = OFF_L1D + 262144;             // 512*512
constexpr size_t OFF_WZR  = OFF_L2D + 262144;             // 2*384*128
constexpr size_t OFF_WHT  = OFF_WZR + 2*384*128;          // 2*384*64
constexpr size_t OFF_BZR  = OFF_WHT + 2*384*64;           // 256
constexpr size_t OFF_BHT  = OFF_BZR + 256;                // 128
constexpr size_t OFF_W1C  = OFF_BHT + 128;                // 8192
constexpr size_t OFF_T1X  = OFF_W1C + 8192;               // B*T*N*C
constexpr size_t OFF_T2X  = OFF_T1X + (size_t)Bn*Tn*NC;
constexpr size_t OFF_H    = OFF_T2X + (size_t)Bn*Tn*NC;   // B*N*H
constexpr size_t OFF_BAR  = OFF_H   + (size_t)Bn*NC;      // barrier counters (ints), 8*32
constexpr size_t OFF_HR   = OFF_BAR + 1024;
constexpr size_t OFF_SP   = OFF_HR  + (size_t)Bn*NC;
constexpr size_t OFF_TP   = OFF_SP  + (size_t)MROWS*Hn;
constexpr size_t OFF_END  = OFF_TP  + (size_t)MROWS*Hn;

// ---------------- setup kernels ----------------
__global__ void k_deg(const float* __restrict__ w, const int* __restrict__ src,
                      float* __restrict__ deg) {
    int e = blockIdx.x * 256 + threadIdx.x;
    if (e < En) atomicAdd(&deg[src[e]], w[e]);
}

__global__ void k_dinv(const float* __restrict__ deg, float* __restrict__ dinv) {
    int n = blockIdx.x * 256 + threadIdx.x;
    if (n < Nn) {
        float d = deg[n];
        dinv[n] = d > 0.f ? rsqrtf(fmaxf(d, 1e-12f)) : 0.f;
    }
}

__global__ void k_nwdense(const float* __restrict__ w, const int* __restrict__ src,
                          const int* __restrict__ dst, const float* __restrict__ dinv,
                          float* __restrict__ L1d) {
    int e = blockIdx.x * 256 + threadIdx.x;
    if (e < En) {
        int s = src[e], d = dst[e];
        float nw = -w[e] * dinv[s] * dinv[d];
        atomicAdd(&L1d[d * Nn + s], nw);
    }
}

// L2 = 2*(L1@L1) - I   (512x512, K=512)
__global__ __launch_bounds__(256) void k_l2(const float* __restrict__ A,
                                            float* __restrict__ C) {
    __shared__ float As[64][33];
    __shared__ float Bs[32][65];
    int t = threadIdx.x;
    int i0 = (blockIdx.x >> 3) * 64;
    int j0 = (blockIdx.x & 7) * 64;
    int tx = t & 15, ty = t >> 4;
    float acc[4][4] = {};
    int ar = t >> 2, ac = (t & 3) * 8;
    int br = t >> 3, bc = (t & 7) * 8;
    for (int kc = 0; kc < 512; kc += 32) {
        float4 a0 = *(const float4*)&A[(size_t)(i0 + ar) * 512 + kc + ac];
        float4 a1 = *(const float4*)&A[(size_t)(i0 + ar) * 512 + kc + ac + 4];
        float4 b0 = *(const float4*)&A[(size_t)(kc + br) * 512 + j0 + bc];
        float4 b1 = *(const float4*)&A[(size_t)(kc + br) * 512 + j0 + bc + 4];
        As[ar][ac+0]=a0.x; As[ar][ac+1]=a0.y; As[ar][ac+2]=a0.z; As[ar][ac+3]=a0.w;
        As[ar][ac+4]=a1.x; As[ar][ac+5]=a1.y; As[ar][ac+6]=a1.z; As[ar][ac+7]=a1.w;
        Bs[br][bc+0]=b0.x; Bs[br][bc+1]=b0.y; Bs[br][bc+2]=b0.z; Bs[br][bc+3]=b0.w;
        Bs[br][bc+4]=b1.x; Bs[br][bc+5]=b1.y; Bs[br][bc+6]=b1.z; Bs[br][bc+7]=b1.w;
        __syncthreads();
#pragma unroll 8
        for (int kk = 0; kk < 32; kk++) {
            float av[4], bv[4];
#pragma unroll
            for (int r = 0; r < 4; r++) av[r] = As[ty * 4 + r][kk];
#pragma unroll
            for (int c = 0; c < 4; c++) bv[c] = Bs[kk][tx * 4 + c];
#pragma unroll
            for (int r = 0; r < 4; r++)
#pragma unroll
                for (int c = 0; c < 4; c++) acc[r][c] += av[r] * bv[c];
        }
        __syncthreads();
    }
#pragma unroll
    for (int r = 0; r < 4; r++)
#pragma unroll
        for (int c = 0; c < 4; c++) {
            int i = i0 + ty * 4 + r, j = j0 + tx * 4 + c;
            C[(size_t)i * 512 + j] = 2.f * acc[r][c] - (i == j ? 1.f : 0.f);
        }
}

// out[slice] = L @ in[slice]
__global__ __launch_bounds__(256) void k_lmm(const float* __restrict__ L,
        const float* __restrict__ in, float* __restrict__ out) {
    int slice = blockIdx.x >> 3;
    int n0 = (blockIdx.x & 7) * 64;
    const float* xs = in + (size_t)slice * NC;
    float* os = out + (size_t)slice * NC;
    __shared__ float As[64][33];
    __shared__ float Bs[32][65];
    int t = threadIdx.x;
    int tx = t & 15, ty = t >> 4;
    float acc[4][4] = {};
    int ar = t >> 2, ac = (t & 3) * 8;
    int br = t >> 3, bc = (t & 7) * 8;
    for (int kc = 0; kc < 512; kc += 32) {
        float4 a0 = *(const float4*)&L[(size_t)(n0 + ar) * 512 + kc + ac];
        float4 a1 = *(const float4*)&L[(size_t)(n0 + ar) * 512 + kc + ac + 4];
        float4 b0 = *(const float4*)&xs[(size_t)(kc + br) * 64 + bc];
        float4 b1 = *(const float4*)&xs[(size_t)(kc + br) * 64 + bc + 4];
        As[ar][ac+0]=a0.x; As[ar][ac+1]=a0.y; As[ar][ac+2]=a0.z; As[ar][ac+3]=a0.w;
        As[ar][ac+4]=a1.x; As[ar][ac+5]=a1.y; As[ar][ac+6]=a1.z; As[ar][ac+7]=a1.w;
        Bs[br][bc+0]=b0.x; Bs[br][bc+1]=b0.y; Bs[br][bc+2]=b0.z; Bs[br][bc+3]=b0.w;
        Bs[br][bc+4]=b1.x; Bs[br][bc+5]=b1.y; Bs[br][bc+6]=b1.z; Bs[br][bc+7]=b1.w;
        __syncthreads();
#pragma unroll 8
        for (int kk = 0; kk < 32; kk++) {
            float av[4], bv[4];
#pragma unroll
            for (int r = 0; r < 4; r++) av[r] = As[ty * 4 + r][kk];
#pragma unroll
            for (int c = 0; c < 4; c++) bv[c] = Bs[kk][tx * 4 + c];
#pragma unroll
            for (int r = 0; r < 4; r++)
#pragma unroll
                for (int c = 0; c < 4; c++) acc[r][c] += av[r] * bv[c];
        }
        __syncthreads();
    }
#pragma unroll
    for (int r = 0; r < 4; r++)
#pragma unroll
        for (int c = 0; c < 4; c++)
            os[(size_t)(n0 + ty * 4 + r) * 64 + tx * 4 + c] = acc[r][c];
}

// repack weights
__global__ void k_repack(const float* __restrict__ Wx, const float* __restrict__ bx,
                         const float* __restrict__ Wh, const float* __restrict__ bh,
                         const float* __restrict__ W1,
                         float* __restrict__ WzrC, float* __restrict__ WhC,
                         float* __restrict__ bzr, float* __restrict__ bht,
                         float* __restrict__ W1cat) {
    int idx = blockIdx.x * 256 + threadIdx.x;
    if (idx < 98304) {
        int l = idx / 49152, r = idx % 49152;
        int k = r / 128, j = r % 128;
        int g = j >> 6, hh = j & 63;
        int kc, c; const float* s;
        if (k < 192) { kc = k / 64; c = k % 64; s = Wh; }
        else { kc = (k - 192) / 64; c = (k - 192) % 64; s = Wx; }
        WzrC[idx] = s[((((size_t)(l*3 + g))*3 + kc)*64 + c)*64 + hh];
    } else if (idx < 147456) {
        int tI = idx - 98304;
        int l = tI / 24576, r = tI % 24576;
        int k = r / 64, hh = r % 64;
        int kc, c; const float* s;
        if (k < 192) { kc = k / 64; c = k % 64; s = Wh; }
        else { kc = (k - 192) / 64; c = (k - 192) % 64; s = Wx; }
        WhC[tI] = s[((((size_t)(l*3 + 2))*3 + kc)*64 + c)*64 + hh];
    } else if (idx < 147712) {
        int tI = idx - 147456;
        int l = tI >> 7, j = tI & 127;
        int g = j >> 6, hh = j & 63;
        bzr[tI] = bh[(l*3 + g)*64 + hh] + bx[(l*3 + g)*64 + hh];
    } else if (idx < 147840) {
        int tI = idx - 147712;
        int l = tI >> 6, hh = tI & 63;
        bht[tI] = bh[(l*3 + 2)*64 + hh] + bx[(l*3 + 2)*64 + hh];
    } else if (idx < 156032) {
        int tI = idx - 147840;
        int c = tI >> 7, j = tI & 127;
        W1cat[tI] = (j < 64) ? W1[c*64 + j] : W1[(64 + c)*64 + (j - 64)];
    }
}

// ================= fused persistent recurrence =================
// PLAIN launch (not cooperative — coop launch silently failed in this harness,
// round 4): 256 blocks x 256 thr, 62.5 KB LDS -> 2 blocks/CU capacity, so all
// 256 blocks are co-resident on the idle 256-CU device; the per-batch spin
// barrier is then safe. Spin has an iteration cap as a hang-safety valve.
// 256 blocks = 8 groups (batch) x 32 blocks (16 rows each).
// LDS (floats): HS@0[32][64]=2048 | LCH@2048 2x[32][18]=1152 | WS@3200 [32][132]=4224
//   (WS aliased as PRED) | OWNh@7424 | OWNx@8448 | OWNt1@9472 | OWNt2@10496 |
//   OWNhr@11520 | OWNz@12544 | U1@13568 | U2@14592 | total 15616 fl = 62.5 KB

__device__ __forceinline__ void group_barrier(int* ctr, int target) {
    __syncthreads();
    if (threadIdx.x == 0) {
        __threadfence();
        atomicAdd(ctr, 1);
        int spins = 0;
        while (atomicAdd(ctr, 0) < target) {
            __builtin_amdgcn_s_sleep(8);
            if (++spins > (1 << 22)) break;   // ~1s valve: fail absmax, not hang
        }
        __threadfence();
    }
    __syncthreads();
}

// U1 = L1[rows,:] @ src_b ; U2 = L2[rows,:] @ src_b   (M=16,N=64,K=512, k-split-2)
__device__ __forceinline__ void phase_A(
        const float* src, const float* __restrict__ L1r, const float* __restrict__ L2r,
        float* HS, float* LCH, float* PRED, float* U1, float* U2,
        int n0, int tid) {
    int cq = tid & 15, rp = (tid >> 4) & 7, kg = tid >> 7;
    int hsr = tid >> 3, hsc = (tid & 7) * 8;
    int lk = tid & 31, lr8 = tid >> 5;
    const size_t lrow0 = (size_t)(n0 + lr8) * 512;
    const size_t lrow1 = (size_t)(n0 + lr8 + 8) * 512;
    float4 ph0 = *(const float4*)&src[(size_t)hsr * 64 + hsc];
    float4 ph1 = *(const float4*)&src[(size_t)hsr * 64 + hsc + 4];
    float pl0 = L1r[lrow0 + lk];
    float pl1 = L1r[lrow1 + lk];
    float pl2 = L2r[lrow0 + lk];
    float pl3 = L2r[lrow1 + lk];
    float acc[2][2][4] = {};
    for (int kc = 0; kc < 512; kc += 32) {
        __syncthreads();
        *(float4*)&HS[hsr * 64 + hsc] = ph0;
        *(float4*)&HS[hsr * 64 + hsc + 4] = ph1;
        LCH[lk * 18 + lr8] = pl0;
        LCH[lk * 18 + lr8 + 8] = pl1;
        LCH[576 + lk * 18 + lr8] = pl2;
        LCH[576 + lk * 18 + lr8 + 8] = pl3;
        __syncthreads();
        if (kc + 32 < 512) {
            int kn = kc + 32;
            ph0 = *(const float4*)&src[(size_t)(kn + hsr) * 64 + hsc];
            ph1 = *(const float4*)&src[(size_t)(kn + hsr) * 64 + hsc + 4];
            pl0 = L1r[lrow0 + kn + lk];
            pl1 = L1r[lrow1 + kn + lk];
            pl2 = L2r[lrow0 + kn + lk];
            pl3 = L2r[lrow1 + kn + lk];
        }
#pragma unroll
        for (int kk = 0; kk < 16; kk++) {
            int k = kg * 16 + kk;
            float2 l1 = *(const float2*)&LCH[k * 18 + rp * 2];
            float2 l2 = *(const float2*)&LCH[576 + k * 18 + rp * 2];
            float4 hv = *(const float4*)&HS[k * 64 + cq * 4];
            float hh[4] = { hv.x, hv.y, hv.z, hv.w };
#pragma unroll
            for (int j = 0; j < 4; j++) {
                acc[0][0][j] += l1.x * hh[j];
                acc[0][1][j] += l1.y * hh[j];
                acc[1][0][j] += l2.x * hh[j];
                acc[1][1][j] += l2.y * hh[j];
            }
        }
    }
#pragma unroll
    for (int m = 0; m < 2; m++)
#pragma unroll
        for (int rr = 0; rr < 2; rr++)
#pragma unroll
            for (int j = 0; j < 4; j++)
                PRED[(m * 2 + kg) * 1024 + (rp * 2 + rr) * 64 + cq * 4 + j] = acc[m][rr][j];
    __syncthreads();
    for (int i = tid; i < 2048; i += 256) {
        int m = i >> 10, rc = i & 1023;
        float v = PRED[m * 2048 + rc] + PRED[m * 2048 + 1024 + rc];
        (m ? U2 : U1)[rc] = v;
    }
    __syncthreads();
}

// zr[16][128] = A[16][384] @ Wz, sigmoid; z->LDS, hr->LDS+global
__device__ __forceinline__ void phase_B1(
        const float* __restrict__ Wz, const float* __restrict__ bz,
        float* WS, const float* const* segs,
        const float* OWNh, float* OWNz, float* OWNhr, float* hrrow, int tid) {
    int c4 = tid & 31, rb = tid >> 5;
    int wk = tid >> 3, wc = (tid & 7) * 16;
    float4 pw[4];
#pragma unroll
    for (int q = 0; q < 4; q++)
        pw[q] = *(const float4*)&Wz[(size_t)wk * 128 + wc + q * 4];
    float acc[2][4] = {};
#pragma unroll
    for (int kt = 0; kt < 12; kt++) {
        __syncthreads();
#pragma unroll
        for (int q = 0; q < 4; q++)
            *(float4*)&WS[wk * 132 + wc + q * 4] = pw[q];
        __syncthreads();
        if (kt < 11) {
#pragma unroll
            for (int q = 0; q < 4; q++)
                pw[q] = *(const float4*)&Wz[(size_t)((kt + 1) * 32 + wk) * 128 + wc + q * 4];
        }
        const float* S = segs[kt >> 1];
        int ks0 = (kt & 1) * 32;
#pragma unroll
        for (int kk = 0; kk < 32; kk++) {
            float a0 = S[(rb * 2 + 0) * 64 + ks0 + kk];
            float a1 = S[(rb * 2 + 1) * 64 + ks0 + kk];
            float4 wv = *(const float4*)&WS[kk * 132 + c4 * 4];
            float wf[4] = { wv.x, wv.y, wv.z, wv.w };
#pragma unroll
            for (int j = 0; j < 4; j++) {
                acc[0][j] += a0 * wf[j];
                acc[1][j] += a1 * wf[j];
            }
        }
    }
#pragma unroll
    for (int rr = 0; rr < 2; rr++) {
        int row = rb * 2 + rr;
#pragma unroll
        for (int j = 0; j < 4; j++) {
            int col = c4 * 4 + j;
            float v = acc[rr][j] + bz[col];
            float s = 1.f / (1.f + __expf(-v));
            if (col < 64) {
                OWNz[row * 64 + col] = s;
            } else {
                float hrv = OWNh[row * 64 + col - 64] * s;
                OWNhr[row * 64 + col - 64] = hrv;
                hrrow[row * 64 + col - 64] = hrv;
            }
        }
    }
}

// ht[16][64] = A[16][384] @ Wh (k-split-2), tanh, GRU update; h->LDS+global
__device__ __forceinline__ void phase_B2(
        const float* __restrict__ Wh_, const float* __restrict__ bh_,
        float* WS, float* PRED, const float* const* segs,
        float* OWNh, const float* OWNz, float* hrow, int tid) {
    int c4 = tid & 15, rb = (tid >> 4) & 7, kg = tid >> 7;
    int wk = tid >> 3, wc = (tid & 7) * 8;
    float4 pw0 = *(const float4*)&Wh_[(size_t)wk * 64 + wc];
    float4 pw1 = *(const float4*)&Wh_[(size_t)wk * 64 + wc + 4];
    float acc[2][4] = {};
#pragma unroll
    for (int kt = 0; kt < 12; kt++) {
        __syncthreads();
        *(float4*)&WS[wk * 68 + wc] = pw0;
        *(float4*)&WS[wk * 68 + wc + 4] = pw1;
        __syncthreads();
        if (kt < 11) {
            pw0 = *(const float4*)&Wh_[(size_t)((kt + 1) * 32 + wk) * 64 + wc];
            pw1 = *(const float4*)&Wh_[(size_t)((kt + 1) * 32 + wk) * 64 + wc + 4];
        }
        const float* S = segs[kt >> 1];
        int ks0 = (kt & 1) * 32 + kg * 16;
        int wb = kg * 16;
#pragma unroll
        for (int kk = 0; kk < 16; kk++) {
            float a0 = S[(rb * 2 + 0) * 64 + ks0 + kk];
            float a1 = S[(rb * 2 + 1) * 64 + ks0 + kk];
            float4 wv = *(const float4*)&WS[(wb + kk) * 68 + c4 * 4];
            float wf[4] = { wv.x, wv.y, wv.z, wv.w };
#pragma unroll
            for (int j = 0; j < 4; j++) {
                acc[0][j] += a0 * wf[j];
                acc[1][j] += a1 * wf[j];
            }
        }
    }
    __syncthreads();   // WS reads done before PRED(=WS) overwrite
#pragma unroll
    for (int rr = 0; rr < 2; rr++)
#pragma unroll
        for (int j = 0; j < 4; j++)
            PRED[kg * 1024 + (rb * 2 + rr) * 64 + c4 * 4 + j] = acc[rr][j];
    __syncthreads();
    for (int i = tid; i < 1024; i += 256) {
        int c = i & 63;
        float ht = tanhf(PRED[i] + PRED[1024 + i] + bh_[c]);
        float zz = OWNz[i];
        float hold = OWNh[i];
        float hn = zz * hold + (1.f - zz) * ht;
        OWNh[i] = hn;
        hrow[i] = hn;
    }
}

__global__ __launch_bounds__(256, 1) void k_recur(
        const float* __restrict__ x, const float* __restrict__ t1x,
        const float* __restrict__ t2x,
        const float* __restrict__ L1, const float* __restrict__ L2,
        const float* __restrict__ Wzr, const float* __restrict__ Wht,
        const float* __restrict__ bzr, const float* __restrict__ bht,
        float* h, float* hr, int* bar) {
    __shared__ float lds[15616];
    float* HS    = lds;
    float* LCH   = lds + 2048;
    float* WS    = lds + 3200;
    float* OWNh  = lds + 7424;
    float* OWNx  = lds + 8448;
    float* OWNt1 = lds + 9472;
    float* OWNt2 = lds + 10496;
    float* OWNhr = lds + 11520;
    float* OWNz  = lds + 12544;
    float* U1    = lds + 13568;
    float* U2    = lds + 14592;
    float* PRED  = WS;

    int tid = threadIdx.x;
    int b = blockIdx.x >> 5;
    int n0 = (blockIdx.x & 31) * 16;
    int* ctr = bar + b * 32;
    const float* hbase  = h  + (size_t)b * NC;
    const float* hrbase = hr + (size_t)b * NC;
    float* hrow  = h  + ((size_t)b * Nn + n0) * 64;
    float* hrrow = hr + ((size_t)b * Nn + n0) * 64;

    for (int i = tid; i < 1024; i += 256) OWNh[i] = 0.f;

    const float* segs1[6] = { OWNh, U1, U2, OWNx, OWNt1, OWNt2 };
    const float* segs2[6] = { OWNhr, U1, U2, OWNx, OWNt1, OWNt2 };

    int nbar = 0;
    for (int t = 0; t < Tn; t++) {
        {
            size_t xoff = ((size_t)(b * Tn + t) * Nn + n0) * 64;
            int r = tid >> 4, c4v = (tid & 15) * 4;
            *(float4*)&OWNx[r * 64 + c4v]  = *(const float4*)&x[xoff + (size_t)r * 64 + c4v];
            *(float4*)&OWNt1[r * 64 + c4v] = *(const float4*)&t1x[xoff + (size_t)r * 64 + c4v];
            *(float4*)&OWNt2[r * 64 + c4v] = *(const float4*)&t2x[xoff + (size_t)r * 64 + c4v];
        }
        for (int l = 0; l < Ln; l++) {
            phase_A(hbase, L1, L2, HS, LCH, PRED, U1, U2, n0, tid);
            phase_B1(Wzr + (size_t)l * 384 * 128, bzr + l * 128, WS, segs1,
                     OWNh, OWNz, OWNhr, hrrow, tid);
            group_barrier(ctr, 32 * (++nbar));
            phase_A(hrbase, L1, L2, HS, LCH, PRED, U1, U2, n0, tid);
            phase_B2(Wht + (size_t)l * 384 * 64, bht + l * 64, WS, PRED, segs2,
                     OWNh, OWNz, hrow, tid);
            group_barrier(ctr, 32 * (++nbar));
        }
    }
}

// ---------------- projections ----------------
__global__ __launch_bounds__(256) void k_proj(
        const float* __restrict__ h, const float* __restrict__ W1cat,
        const float* __restrict__ b1,
        float* __restrict__ sproj, float* __restrict__ tproj) {
    __shared__ float As[16][33];
    __shared__ float Ws[16 * 128];
    int tid = threadIdx.x;
    int row0 = blockIdx.x * 32;
    const float* hp = h + (size_t)row0 * 64;
    float acc[2][8] = {};
    int tx = tid & 15, ty = tid >> 4;
    int lr = tid >> 3;
    int lk = (tid & 7) * 2;
    int wk = tid >> 4;
    int wc = (tid & 15) * 8;
    for (int kt = 0; kt < 4; kt++) {
        int c0 = kt * 16;
        float2 a2 = *(const float2*)&hp[lr * 64 + c0 + lk];
        const float4* wsrc = (const float4*)&W1cat[(size_t)(kt * 16 + wk) * 128 + wc];
        float4 w0 = wsrc[0], w1 = wsrc[1];
        As[lk][lr] = a2.x;
        As[lk + 1][lr] = a2.y;
        *(float4*)&Ws[wk * 128 + wc] = w0;
        *(float4*)&Ws[wk * 128 + wc + 4] = w1;
        __syncthreads();
#pragma unroll
        for (int kk = 0; kk < 16; kk++) {
            float a0 = As[kk][ty * 2 + 0];
            float a1 = As[kk][ty * 2 + 1];
            float4 p0 = *(const float4*)&Ws[kk * 128 + tx * 8];
            float4 p1 = *(const float4*)&Ws[kk * 128 + tx * 8 + 4];
            float w[8] = { p0.x, p0.y, p0.z, p0.w, p1.x, p1.y, p1.z, p1.w };
#pragma unroll
            for (int cc = 0; cc < 8; cc++) {
                acc[0][cc] += a0 * w[cc];
                acc[1][cc] += a1 * w[cc];
            }
        }
        __syncthreads();
    }
#pragma unroll
    for (int rr = 0; rr < 2; rr++) {
        int row = row0 + ty * 2 + rr;
#pragma unroll
        for (int cc = 0; cc < 8; cc++) {
            int col = tx * 8 + cc;
            float v = acc[rr][cc];
            if (col < 64) sproj[(size_t)row * 64 + col] = v + b1[col];
            else tproj[(size_t)row * 64 + (col - 64)] = v;
        }
    }
}

// ---------------- logits ----------------
__global__ __launch_bounds__(256) void k_logits(
        const float* __restrict__ sproj, const float* __restrict__ tproj,
        const float* __restrict__ W2, const float* __restrict__ b2,
        float* __restrict__ out) {
    __shared__ float sp[32 * 64];
    __shared__ float tp[64 * 65];
    __shared__ float w2s[64];
    int tid = threadIdx.x;
    int bb = blockIdx.x >> 7;
    int st = (blockIdx.x >> 3) & 15;
    int tt = blockIdx.x & 7;
    const float* spg = sproj + ((size_t)bb * Nn + st * 32) * 64;
    const float* tpg = tproj + ((size_t)bb * Nn + tt * 64) * 64;
    for (int i = tid; i < 2048; i += 256) sp[i] = spg[i];
    for (int i = tid; i < 4096; i += 256) {
        int tl = i >> 6, hh = i & 63;
        tp[tl * 65 + hh] = tpg[i];
    }
    if (tid < 64) w2s[tid] = W2[tid];
    __syncthreads();
    float bias = *b2;
    int tl = tid & 63, sg = tid >> 6;
    for (int si = 0; si < 8; si++) {
        int s = sg * 8 + si;
        float acc = bias;
#pragma unroll 8
        for (int hh = 0; hh < 64; hh++) {
            float v = sp[s * 64 + hh] + tp[tl * 65 + hh];
            acc += fmaxf(v, 0.f) * w2s[hh];
        }
        out[(size_t)bb * Nn * Nn + (size_t)(st * 32 + s) * Nn + tt * 64 + tl] = acc;
    }
}

// ---------------- host ----------------
extern "C" void kernel_launch(void* const* d_in, const int* in_sizes, int n_in,
                              void* d_out, int out_size, void* d_ws, size_t ws_size,
                              hipStream_t stream) {
    const float* x  = (const float*)d_in[0];
    const float* ew = (const float*)d_in[1];
    const float* Wx = (const float*)d_in[2];
    const float* bx = (const float*)d_in[3];
    const float* Wh = (const float*)d_in[4];
    const float* bh = (const float*)d_in[5];
    const float* W1 = (const float*)d_in[6];
    const float* b1 = (const float*)d_in[7];
    const float* W2 = (const float*)d_in[8];
    const float* b2 = (const float*)d_in[9];
    const int* ei   = (const int*)d_in[10];
    const int* esrc = ei;
    const int* edst = ei + En;

    float* ws = (float*)d_ws;
    float* deg   = ws + OFF_DEG;
    float* dinv  = ws + OFF_DINV;
    float* L1d   = ws + OFF_L1D;
    float* L2d   = ws + OFF_L2D;
    float* WzrC  = ws + OFF_WZR;
    float* WhC   = ws + OFF_WHT;
    float* bzr   = ws + OFF_BZR;
    float* bht   = ws + OFF_BHT;
    float* W1cat = ws + OFF_W1C;
    float* T1x   = ws + OFF_T1X;
    float* T2x   = ws + OFF_T2X;
    float* h     = ws + OFF_H;
    int*   barp  = (int*)(ws + OFF_BAR);
    float* hr    = ws + OFF_HR;
    float* sproj = ws + OFF_SP;
    float* tproj = ws + OFF_TP;
    float* out   = (float*)d_out;

    hipMemsetAsync(deg, 0, 512 * sizeof(float), stream);
    hipMemsetAsync(L1d, 0, (size_t)Nn * Nn * sizeof(float), stream);
    hipMemsetAsync(h, 0, (size_t)Bn * NC * sizeof(float), stream);
    hipMemsetAsync(barp, 0, 8 * 32 * sizeof(int), stream);

    k_deg<<<64, 256, 0, stream>>>(ew, esrc, deg);
    k_dinv<<<2, 256, 0, stream>>>(deg, dinv);
    k_nwdense<<<64, 256, 0, stream>>>(ew, esrc, edst, dinv, L1d);
    k_l2<<<64, 256, 0, stream>>>(L1d, L2d);
    k_repack<<<(156032 + 255) / 256, 256, 0, stream>>>(Wx, bx, Wh, bh, W1,
                                                       WzrC, WhC, bzr, bht, W1cat);

    k_lmm<<<Bn * Tn * 8, 256, 0, stream>>>(L1d, x, T1x);
    k_lmm<<<Bn * Tn * 8, 256, 0, stream>>>(L2d, x, T2x);

    // whole recurrence in one PLAIN dispatch (all 256 blocks co-resident:
    // 62.5 KB LDS => 2 blocks/CU capacity, grid == CU count)
    k_recur<<<256, 256, 0, stream>>>(x, T1x, T2x, L1d, L2d, WzrC, WhC,
                                     bzr, bht, h, hr, barp);

    k_proj<<<128, 256, 0, stream>>>(h, W1cat, b1, sproj, tproj);
    k_logits<<<Bn * 16 * 8, 256, 0, stream>>>(sproj, tproj, W2, b2, out);
}

// Round 6
// 2267.487 us; speedup vs baseline: 22.3077x; 22.3077x over previous
//
#include <hip/hip_runtime.h>

// Problem constants
constexpr int Bn = 8, Tn = 16, Nn = 512, Cn = 64, Hn = 64, En = 16384, Ln = 2;
constexpr int NC = Nn * Cn;           // 32768
constexpr int MROWS = Bn * Nn;        // 4096

// ---------------- workspace layout (in floats) ----------------
constexpr size_t OFF_DEG  = 0;                            // 512
constexpr size_t OFF_DINV = 512;                          // 512
constexpr size_t OFF_L1D  = 1024;                         // 512*512
constexpr size_t OFF_L2D  = OFF_L1D + 262144;             // 512*512
constexpr size_t OFF_WZR  = OFF_L2D + 262144;             // 2*384*128
constexpr size_t OFF_WHT  = OFF_WZR + 2*384*128;          // 2*384*64
constexpr size_t OFF_BZR  = OFF_WHT + 2*384*64;           // 256
constexpr size_t OFF_BHT  = OFF_BZR + 256;                // 128
constexpr size_t OFF_W1C  = OFF_BHT + 128;                // 8192
constexpr size_t OFF_T1X  = OFF_W1C + 8192;               // B*T*N*C
constexpr size_t OFF_T2X  = OFF_T1X + (size_t)Bn*Tn*NC;
constexpr size_t OFF_H    = OFF_T2X + (size_t)Bn*Tn*NC;   // B*N*H
constexpr size_t OFF_Z    = OFF_H   + (size_t)Bn*NC;
constexpr size_t OFF_HR   = OFF_Z   + (size_t)Bn*NC;
constexpr size_t OFF_SP   = OFF_HR  + (size_t)Bn*NC;
constexpr size_t OFF_TP   = OFF_SP  + (size_t)MROWS*Hn;
constexpr size_t OFF_END  = OFF_TP  + (size_t)MROWS*Hn;

// ---------------- setup kernels ----------------
__global__ void k_deg(const float* __restrict__ w, const int* __restrict__ src,
                      float* __restrict__ deg) {
    int e = blockIdx.x * 256 + threadIdx.x;
    if (e < En) atomicAdd(&deg[src[e]], w[e]);
}

__global__ void k_dinv(const float* __restrict__ deg, float* __restrict__ dinv) {
    int n = blockIdx.x * 256 + threadIdx.x;
    if (n < Nn) {
        float d = deg[n];
        dinv[n] = d > 0.f ? rsqrtf(fmaxf(d, 1e-12f)) : 0.f;
    }
}

__global__ void k_nwdense(const float* __restrict__ w, const int* __restrict__ src,
                          const int* __restrict__ dst, const float* __restrict__ dinv,
                          float* __restrict__ L1d) {
    int e = blockIdx.x * 256 + threadIdx.x;
    if (e < En) {
        int s = src[e], d = dst[e];
        float nw = -w[e] * dinv[s] * dinv[d];
        atomicAdd(&L1d[d * Nn + s], nw);
    }
}

// L2 = 2*(L1@L1) - I   (512x512, K=512)
__global__ __launch_bounds__(256) void k_l2(const float* __restrict__ A,
                                            float* __restrict__ C) {
    __shared__ float As[64][33];
    __shared__ float Bs[32][65];
    int t = threadIdx.x;
    int i0 = (blockIdx.x >> 3) * 64;
    int j0 = (blockIdx.x & 7) * 64;
    int tx = t & 15, ty = t >> 4;
    float acc[4][4] = {};
    int ar = t >> 2, ac = (t & 3) * 8;
    int br = t >> 3, bc = (t & 7) * 8;
    for (int kc = 0; kc < 512; kc += 32) {
        float4 a0 = *(const float4*)&A[(size_t)(i0 + ar) * 512 + kc + ac];
        float4 a1 = *(const float4*)&A[(size_t)(i0 + ar) * 512 + kc + ac + 4];
        float4 b0 = *(const float4*)&A[(size_t)(kc + br) * 512 + j0 + bc];
        float4 b1 = *(const float4*)&A[(size_t)(kc + br) * 512 + j0 + bc + 4];
        As[ar][ac+0]=a0.x; As[ar][ac+1]=a0.y; As[ar][ac+2]=a0.z; As[ar][ac+3]=a0.w;
        As[ar][ac+4]=a1.x; As[ar][ac+5]=a1.y; As[ar][ac+6]=a1.z; As[ar][ac+7]=a1.w;
        Bs[br][bc+0]=b0.x; Bs[br][bc+1]=b0.y; Bs[br][bc+2]=b0.z; Bs[br][bc+3]=b0.w;
        Bs[br][bc+4]=b1.x; Bs[br][bc+5]=b1.y; Bs[br][bc+6]=b1.z; Bs[br][bc+7]=b1.w;
        __syncthreads();
#pragma unroll 8
        for (int kk = 0; kk < 32; kk++) {
            float av[4], bv[4];
#pragma unroll
            for (int r = 0; r < 4; r++) av[r] = As[ty * 4 + r][kk];
#pragma unroll
            for (int c = 0; c < 4; c++) bv[c] = Bs[kk][tx * 4 + c];
#pragma unroll
            for (int r = 0; r < 4; r++)
#pragma unroll
                for (int c = 0; c < 4; c++) acc[r][c] += av[r] * bv[c];
        }
        __syncthreads();
    }
#pragma unroll
    for (int r = 0; r < 4; r++)
#pragma unroll
        for (int c = 0; c < 4; c++) {
            int i = i0 + ty * 4 + r, j = j0 + tx * 4 + c;
            C[(size_t)i * 512 + j] = 2.f * acc[r][c] - (i == j ? 1.f : 0.f);
        }
}

// fused: o1 = L1 @ in[slice], o2 = L2 @ in[slice] (shares x staging)
__global__ __launch_bounds__(256) void k_lmm2(const float* __restrict__ L1,
        const float* __restrict__ L2, const float* __restrict__ in,
        float* __restrict__ o1, float* __restrict__ o2) {
    int slice = blockIdx.x >> 3;
    int n0 = (blockIdx.x & 7) * 64;
    const float* xs = in + (size_t)slice * NC;
    float* os1 = o1 + (size_t)slice * NC;
    float* os2 = o2 + (size_t)slice * NC;
    __shared__ float As1[64][33];
    __shared__ float As2[64][33];
    __shared__ float Bs[32][65];
    int t = threadIdx.x;
    int tx = t & 15, ty = t >> 4;
    float acc1[4][4] = {}, acc2[4][4] = {};
    int ar = t >> 2, ac = (t & 3) * 8;
    int br = t >> 3, bc = (t & 7) * 8;
    for (int kc = 0; kc < 512; kc += 32) {
        float4 a0 = *(const float4*)&L1[(size_t)(n0 + ar) * 512 + kc + ac];
        float4 a1 = *(const float4*)&L1[(size_t)(n0 + ar) * 512 + kc + ac + 4];
        float4 c0 = *(const float4*)&L2[(size_t)(n0 + ar) * 512 + kc + ac];
        float4 c1 = *(const float4*)&L2[(size_t)(n0 + ar) * 512 + kc + ac + 4];
        float4 b0 = *(const float4*)&xs[(size_t)(kc + br) * 64 + bc];
        float4 b1 = *(const float4*)&xs[(size_t)(kc + br) * 64 + bc + 4];
        As1[ar][ac+0]=a0.x; As1[ar][ac+1]=a0.y; As1[ar][ac+2]=a0.z; As1[ar][ac+3]=a0.w;
        As1[ar][ac+4]=a1.x; As1[ar][ac+5]=a1.y; As1[ar][ac+6]=a1.z; As1[ar][ac+7]=a1.w;
        As2[ar][ac+0]=c0.x; As2[ar][ac+1]=c0.y; As2[ar][ac+2]=c0.z; As2[ar][ac+3]=c0.w;
        As2[ar][ac+4]=c1.x; As2[ar][ac+5]=c1.y; As2[ar][ac+6]=c1.z; As2[ar][ac+7]=c1.w;
        Bs[br][bc+0]=b0.x; Bs[br][bc+1]=b0.y; Bs[br][bc+2]=b0.z; Bs[br][bc+3]=b0.w;
        Bs[br][bc+4]=b1.x; Bs[br][bc+5]=b1.y; Bs[br][bc+6]=b1.z; Bs[br][bc+7]=b1.w;
        __syncthreads();
#pragma unroll 4
        for (int kk = 0; kk < 32; kk++) {
            float av1[4], av2[4], bv[4];
#pragma unroll
            for (int r = 0; r < 4; r++) { av1[r] = As1[ty*4+r][kk]; av2[r] = As2[ty*4+r][kk]; }
#pragma unroll
            for (int c = 0; c < 4; c++) bv[c] = Bs[kk][tx * 4 + c];
#pragma unroll
            for (int r = 0; r < 4; r++)
#pragma unroll
                for (int c = 0; c < 4; c++) {
                    acc1[r][c] += av1[r] * bv[c];
                    acc2[r][c] += av2[r] * bv[c];
                }
        }
        __syncthreads();
    }
#pragma unroll
    for (int r = 0; r < 4; r++)
#pragma unroll
        for (int c = 0; c < 4; c++) {
            os1[(size_t)(n0 + ty * 4 + r) * 64 + tx * 4 + c] = acc1[r][c];
            os2[(size_t)(n0 + ty * 4 + r) * 64 + tx * 4 + c] = acc2[r][c];
        }
}

// repack weights
__global__ void k_repack(const float* __restrict__ Wx, const float* __restrict__ bx,
                         const float* __restrict__ Wh, const float* __restrict__ bh,
                         const float* __restrict__ W1,
                         float* __restrict__ WzrC, float* __restrict__ WhC,
                         float* __restrict__ bzr, float* __restrict__ bht,
                         float* __restrict__ W1cat) {
    int idx = blockIdx.x * 256 + threadIdx.x;
    if (idx < 98304) {
        int l = idx / 49152, r = idx % 49152;
        int k = r / 128, j = r % 128;
        int g = j >> 6, hh = j & 63;
        int kc, c; const float* s;
        if (k < 192) { kc = k / 64; c = k % 64; s = Wh; }
        else { kc = (k - 192) / 64; c = (k - 192) % 64; s = Wx; }
        WzrC[idx] = s[((((size_t)(l*3 + g))*3 + kc)*64 + c)*64 + hh];
    } else if (idx < 147456) {
        int tI = idx - 98304;
        int l = tI / 24576, r = tI % 24576;
        int k = r / 64, hh = r % 64;
        int kc, c; const float* s;
        if (k < 192) { kc = k / 64; c = k % 64; s = Wh; }
        else { kc = (k - 192) / 64; c = (k - 192) % 64; s = Wx; }
        WhC[tI] = s[((((size_t)(l*3 + 2))*3 + kc)*64 + c)*64 + hh];
    } else if (idx < 147712) {
        int tI = idx - 147456;
        int l = tI >> 7, j = tI & 127;
        int g = j >> 6, hh = j & 63;
        bzr[tI] = bh[(l*3 + g)*64 + hh] + bx[(l*3 + g)*64 + hh];
    } else if (idx < 147840) {
        int tI = idx - 147712;
        int l = tI >> 6, hh = tI & 63;
        bht[tI] = bh[(l*3 + 2)*64 + hh] + bx[(l*3 + 2)*64 + hh];
    } else if (idx < 156032) {
        int tI = idx - 147840;
        int c = tI >> 7, j = tI & 127;
        W1cat[tI] = (j < 64) ? W1[c*64 + j] : W1[(64 + c)*64 + (j - 64)];
    }
}

// ================= cell kernels: 512 blocks x 8 rows (2+ blocks/CU) =================
// LDS (floats): HS@0 [32][68]=2176 | LCH@2176 [2][320]=640 | WS@2816 (B1 4224 / B2 2176)
//   ASEG@7040 [6][512]=3072 (segs: own, U1, U2, x, t1x, t2x) ; total 10112 fl = 40.4 KB.
// PRED aliases lds[0..4096) during phase-A reduce, lds[0..2048) during phase-B reduce.

// U1 = L1[rows,:]@src_b, U2 = L2[rows,:]@src_b  (M=8, N=64, K=512, k-split-4)
__device__ __forceinline__ void phase_A8(
        const float* __restrict__ src,
        const float* __restrict__ L1r, const float* __restrict__ L2r,
        float* lds, int n0, int tid) {
    float* HS   = lds;
    float* LCH  = lds + 2176;
    float* PRED = lds;
    float* U1   = lds + 7040 + 512;
    float* U2   = lds + 7040 + 1024;
    int cq = tid & 15, rp = (tid >> 4) & 3, kg = tid >> 6;     // kg 0..3
    int hsr = tid >> 3, hsc = (tid & 7) * 8;
    int idx = tid & 127;
    int lk = idx & 31, lr4 = idx >> 5;                          // lr4 0..3
    const float* Lsrc = (tid < 128) ? L1r : L2r;
    float* Ldst = (tid < 128) ? LCH : LCH + 320;
    size_t lrowA = (size_t)(n0 + lr4) * 512;
    size_t lrowB = (size_t)(n0 + lr4 + 4) * 512;
    float4 ph0 = *(const float4*)&src[(size_t)hsr * 64 + hsc];
    float4 ph1 = *(const float4*)&src[(size_t)hsr * 64 + hsc + 4];
    float plA = Lsrc[lrowA + lk];
    float plB = Lsrc[lrowB + lk];
    float acc[2][2][4] = {};
    for (int kc = 0; kc < 512; kc += 32) {
        __syncthreads();
        *(float4*)&HS[hsr * 68 + hsc] = ph0;
        *(float4*)&HS[hsr * 68 + hsc + 4] = ph1;
        Ldst[lk * 10 + lr4] = plA;
        Ldst[lk * 10 + lr4 + 4] = plB;
        __syncthreads();
        if (kc + 32 < 512) {
            int kn = kc + 32;
            ph0 = *(const float4*)&src[(size_t)(kn + hsr) * 64 + hsc];
            ph1 = *(const float4*)&src[(size_t)(kn + hsr) * 64 + hsc + 4];
            plA = Lsrc[lrowA + kn + lk];
            plB = Lsrc[lrowB + kn + lk];
        }
#pragma unroll
        for (int kk = 0; kk < 8; kk++) {
            int k = kg * 8 + kk;
            float2 l1 = *(const float2*)&LCH[k * 10 + rp * 2];
            float2 l2 = *(const float2*)&LCH[320 + k * 10 + rp * 2];
            float4 hv = *(const float4*)&HS[k * 68 + cq * 4];
            float hh[4] = { hv.x, hv.y, hv.z, hv.w };
#pragma unroll
            for (int j = 0; j < 4; j++) {
                acc[0][0][j] += l1.x * hh[j];
                acc[0][1][j] += l1.y * hh[j];
                acc[1][0][j] += l2.x * hh[j];
                acc[1][1][j] += l2.y * hh[j];
            }
        }
    }
    __syncthreads();   // last chunk reads done before PRED(=HS/LCH/WS-head) overwrite
#pragma unroll
    for (int m = 0; m < 2; m++)
#pragma unroll
        for (int rr = 0; rr < 2; rr++)
#pragma unroll
            for (int j = 0; j < 4; j++)
                PRED[((m * 4 + kg) * 8 + rp * 2 + rr) * 64 + cq * 4 + j] = acc[m][rr][j];
    __syncthreads();
    for (int i = tid; i < 1024; i += 256) {
        int m = i >> 9, rc = i & 511;
        float v = PRED[(m * 4 + 0) * 512 + rc] + PRED[(m * 4 + 1) * 512 + rc]
                + PRED[(m * 4 + 2) * 512 + rc] + PRED[(m * 4 + 3) * 512 + rc];
        (m ? U2 : U1)[rc] = v;
    }
    __syncthreads();
}

// stage1: z,r = sigmoid([h,u1,u2,x,t1x,t2x]@Wzr + b); z->global, hr=h*r->global
__global__ __launch_bounds__(256) void k_cell1(
        const float* __restrict__ h, const float* __restrict__ x,
        const float* __restrict__ t1x, const float* __restrict__ t2x,
        const float* __restrict__ L1, const float* __restrict__ L2,
        const float* __restrict__ W, const float* __restrict__ bias,
        float* __restrict__ z, float* __restrict__ hr, int t) {
    __shared__ float lds[10112];
    float* WS   = lds + 2816;
    float* ASEG = lds + 7040;
    float* PRED = lds;
    int tid = threadIdx.x;
    int b = blockIdx.x >> 6;
    int n0 = (blockIdx.x & 63) * 8;
    const float* hb = h + (size_t)b * NC;
    size_t hoff = ((size_t)b * Nn + n0) * 64;
    size_t xoff = ((size_t)(b * Tn + t) * Nn + n0) * 64;
    {
        int p = tid * 2;
        *(float2*)&ASEG[0 * 512 + p] = *(const float2*)&h[hoff + p];
        *(float2*)&ASEG[3 * 512 + p] = *(const float2*)&x[xoff + p];
        *(float2*)&ASEG[4 * 512 + p] = *(const float2*)&t1x[xoff + p];
        *(float2*)&ASEG[5 * 512 + p] = *(const float2*)&t2x[xoff + p];
    }
    phase_A8(hb, L1, L2, lds, n0, tid);

    // phase B1: zr[8][128] = A[8][384] @ W[384][128], k-split-2
    int c4 = tid & 31, rp = (tid >> 5) & 3, kg = tid >> 7;   // kg 0..1
    int wk = tid >> 3, wc = (tid & 7) * 16;
    float4 pw[4];
#pragma unroll
    for (int q = 0; q < 4; q++)
        pw[q] = *(const float4*)&W[(size_t)wk * 128 + wc + q * 4];
    float acc[2][4] = {};
#pragma unroll
    for (int kt = 0; kt < 12; kt++) {
        __syncthreads();
#pragma unroll
        for (int q = 0; q < 4; q++)
            *(float4*)&WS[wk * 132 + wc + q * 4] = pw[q];
        __syncthreads();
        if (kt < 11) {
#pragma unroll
            for (int q = 0; q < 4; q++)
                pw[q] = *(const float4*)&W[(size_t)((kt + 1) * 32 + wk) * 128 + wc + q * 4];
        }
        const float* S = ASEG + (kt >> 1) * 512;
        int ks0 = (kt & 1) * 32;
#pragma unroll
        for (int kk = 0; kk < 16; kk++) {
            int k = kg * 16 + kk;
            float a0 = S[(rp * 2 + 0) * 64 + ks0 + k];
            float a1 = S[(rp * 2 + 1) * 64 + ks0 + k];
            float4 wv = *(const float4*)&WS[k * 132 + c4 * 4];
            float wf[4] = { wv.x, wv.y, wv.z, wv.w };
#pragma unroll
            for (int j = 0; j < 4; j++) {
                acc[0][j] += a0 * wf[j];
                acc[1][j] += a1 * wf[j];
            }
        }
    }
    // PRED(B) = lds[0..2048) — no overlap with WS@2816 or ASEG
#pragma unroll
    for (int rr = 0; rr < 2; rr++)
#pragma unroll
        for (int j = 0; j < 4; j++)
            PRED[kg * 1024 + (rp * 2 + rr) * 128 + c4 * 4 + j] = acc[rr][j];
    __syncthreads();
    for (int i = tid; i < 1024; i += 256) {
        int r = i >> 7, c = i & 127;
        float v = PRED[i] + PRED[1024 + i] + bias[c];
        float s = 1.f / (1.f + __expf(-v));
        size_t grow = ((size_t)(b * Nn + n0 + r)) * 64;
        if (c < 64) z[grow + c] = s;
        else hr[grow + (c - 64)] = ASEG[r * 64 + (c - 64)] * s;
    }
}

// stage2: ht = tanh([hr,v1,v2,x,t1x,t2x]@Wht + b); h = z*h + (1-z)*ht
__global__ __launch_bounds__(256) void k_cell2(
        const float* __restrict__ hrp, const float* __restrict__ x,
        const float* __restrict__ t1x, const float* __restrict__ t2x,
        const float* __restrict__ L1, const float* __restrict__ L2,
        const float* __restrict__ W, const float* __restrict__ bias,
        const float* __restrict__ z, float* __restrict__ h, int t) {
    __shared__ float lds[10112];
    float* WS   = lds + 2816;
    float* ASEG = lds + 7040;
    float* PRED = lds;
    int tid = threadIdx.x;
    int b = blockIdx.x >> 6;
    int n0 = (blockIdx.x & 63) * 8;
    const float* hb = hrp + (size_t)b * NC;
    size_t hoff = ((size_t)b * Nn + n0) * 64;
    size_t xoff = ((size_t)(b * Tn + t) * Nn + n0) * 64;
    {
        int p = tid * 2;
        *(float2*)&ASEG[0 * 512 + p] = *(const float2*)&hrp[hoff + p];
        *(float2*)&ASEG[3 * 512 + p] = *(const float2*)&x[xoff + p];
        *(float2*)&ASEG[4 * 512 + p] = *(const float2*)&t1x[xoff + p];
        *(float2*)&ASEG[5 * 512 + p] = *(const float2*)&t2x[xoff + p];
    }
    phase_A8(hb, L1, L2, lds, n0, tid);

    // phase B2: ht[8][64] = A[8][384] @ W[384][64], k-split-4
    int c4 = tid & 15, rp = (tid >> 4) & 3, kg = tid >> 6;   // kg 0..3
    int wk = tid >> 3, wc = (tid & 7) * 8;
    float4 pw0 = *(const float4*)&W[(size_t)wk * 64 + wc];
    float4 pw1 = *(const float4*)&W[(size_t)wk * 64 + wc + 4];
    float acc[2][4] = {};
#pragma unroll
    for (int kt = 0; kt < 12; kt++) {
        __syncthreads();
        *(float4*)&WS[wk * 68 + wc] = pw0;
        *(float4*)&WS[wk * 68 + wc + 4] = pw1;
        __syncthreads();
        if (kt < 11) {
            pw0 = *(const float4*)&W[(size_t)((kt + 1) * 32 + wk) * 64 + wc];
            pw1 = *(const float4*)&W[(size_t)((kt + 1) * 32 + wk) * 64 + wc + 4];
        }
        const float* S = ASEG + (kt >> 1) * 512;
        int ks0 = (kt & 1) * 32;
#pragma unroll
        for (int kk = 0; kk < 8; kk++) {
            int k = kg * 8 + kk;
            float a0 = S[(rp * 2 + 0) * 64 + ks0 + k];
            float a1 = S[(rp * 2 + 1) * 64 + ks0 + k];
            float4 wv = *(const float4*)&WS[k * 68 + c4 * 4];
            float wf[4] = { wv.x, wv.y, wv.z, wv.w };
#pragma unroll
            for (int j = 0; j < 4; j++) {
                acc[0][j] += a0 * wf[j];
                acc[1][j] += a1 * wf[j];
            }
        }
    }
#pragma unroll
    for (int rr = 0; rr < 2; rr++)
#pragma unroll
        for (int j = 0; j < 4; j++)
            PRED[kg * 512 + (rp * 2 + rr) * 64 + c4 * 4 + j] = acc[rr][j];
    __syncthreads();
    for (int i = tid; i < 512; i += 256) {
        int r = i >> 6, c = i & 63;
        float v = PRED[i] + PRED[512 + i] + PRED[1024 + i] + PRED[1536 + i] + bias[c];
        float ht = tanhf(v);
        size_t p = ((size_t)(b * Nn + n0 + r)) * 64 + c;
        float zz = z[p], hold = h[p];
        h[p] = zz * hold + (1.f - zz) * ht;
    }
}

// ---------------- projections ----------------
__global__ __launch_bounds__(256) void k_proj(
        const float* __restrict__ h, const float* __restrict__ W1cat,
        const float* __restrict__ b1,
        float* __restrict__ sproj, float* __restrict__ tproj) {
    __shared__ float As[16][33];
    __shared__ float Ws[16 * 128];
    int tid = threadIdx.x;
    int row0 = blockIdx.x * 32;
    const float* hp = h + (size_t)row0 * 64;
    float acc[2][8] = {};
    int tx = tid & 15, ty = tid >> 4;
    int lr = tid >> 3;
    int lk = (tid & 7) * 2;
    int wk = tid >> 4;
    int wc = (tid & 15) * 8;
    for (int kt = 0; kt < 4; kt++) {
        int c0 = kt * 16;
        float2 a2 = *(const float2*)&hp[lr * 64 + c0 + lk];
        const float4* wsrc = (const float4*)&W1cat[(size_t)(kt * 16 + wk) * 128 + wc];
        float4 w0 = wsrc[0], w1 = wsrc[1];
        As[lk][lr] = a2.x;
        As[lk + 1][lr] = a2.y;
        *(float4*)&Ws[wk * 128 + wc] = w0;
        *(float4*)&Ws[wk * 128 + wc + 4] = w1;
        __syncthreads();
#pragma unroll
        for (int kk = 0; kk < 16; kk++) {
            float a0 = As[kk][ty * 2 + 0];
            float a1 = As[kk][ty * 2 + 1];
            float4 p0 = *(const float4*)&Ws[kk * 128 + tx * 8];
            float4 p1 = *(const float4*)&Ws[kk * 128 + tx * 8 + 4];
            float w[8] = { p0.x, p0.y, p0.z, p0.w, p1.x, p1.y, p1.z, p1.w };
#pragma unroll
            for (int cc = 0; cc < 8; cc++) {
                acc[0][cc] += a0 * w[cc];
                acc[1][cc] += a1 * w[cc];
            }
        }
        __syncthreads();
    }
#pragma unroll
    for (int rr = 0; rr < 2; rr++) {
        int row = row0 + ty * 2 + rr;
#pragma unroll
        for (int cc = 0; cc < 8; cc++) {
            int col = tx * 8 + cc;
            float v = acc[rr][cc];
            if (col < 64) sproj[(size_t)row * 64 + col] = v + b1[col];
            else tproj[(size_t)row * 64 + (col - 64)] = v;
        }
    }
}

// ---------------- logits ----------------
__global__ __launch_bounds__(256) void k_logits(
        const float* __restrict__ sproj, const float* __restrict__ tproj,
        const float* __restrict__ W2, const float* __restrict__ b2,
        float* __restrict__ out) {
    __shared__ float sp[32 * 64];
    __shared__ float tp[64 * 65];
    __shared__ float w2s[64];
    int tid = threadIdx.x;
    int bb = blockIdx.x >> 7;
    int st = (blockIdx.x >> 3) & 15;
    int tt = blockIdx.x & 7;
    const float* spg = sproj + ((size_t)bb * Nn + st * 32) * 64;
    const float* tpg = tproj + ((size_t)bb * Nn + tt * 64) * 64;
    for (int i = tid; i < 2048; i += 256) sp[i] = spg[i];
    for (int i = tid; i < 4096; i += 256) {
        int tl = i >> 6, hh = i & 63;
        tp[tl * 65 + hh] = tpg[i];
    }
    if (tid < 64) w2s[tid] = W2[tid];
    __syncthreads();
    float bias = *b2;
    int tl = tid & 63, sg = tid >> 6;
    for (int si = 0; si < 8; si++) {
        int s = sg * 8 + si;
        float acc = bias;
#pragma unroll 8
        for (int hh = 0; hh < 64; hh++) {
            float v = sp[s * 64 + hh] + tp[tl * 65 + hh];
            acc += fmaxf(v, 0.f) * w2s[hh];
        }
        out[(size_t)bb * Nn * Nn + (size_t)(st * 32 + s) * Nn + tt * 64 + tl] = acc;
    }
}

// ---------------- host ----------------
extern "C" void kernel_launch(void* const* d_in, const int* in_sizes, int n_in,
                              void* d_out, int out_size, void* d_ws, size_t ws_size,
                              hipStream_t stream) {
    const float* x  = (const float*)d_in[0];
    const float* ew = (const float*)d_in[1];
    const float* Wx = (const float*)d_in[2];
    const float* bx = (const float*)d_in[3];
    const float* Wh = (const float*)d_in[4];
    const float* bh = (const float*)d_in[5];
    const float* W1 = (const float*)d_in[6];
    const float* b1 = (const float*)d_in[7];
    const float* W2 = (const float*)d_in[8];
    const float* b2 = (const float*)d_in[9];
    const int* ei   = (const int*)d_in[10];
    const int* esrc = ei;
    const int* edst = ei + En;

    float* ws = (float*)d_ws;
    float* deg   = ws + OFF_DEG;
    float* dinv  = ws + OFF_DINV;
    float* L1d   = ws + OFF_L1D;
    float* L2d   = ws + OFF_L2D;
    float* WzrC  = ws + OFF_WZR;
    float* WhC   = ws + OFF_WHT;
    float* bzr   = ws + OFF_BZR;
    float* bht   = ws + OFF_BHT;
    float* W1cat = ws + OFF_W1C;
    float* T1x   = ws + OFF_T1X;
    float* T2x   = ws + OFF_T2X;
    float* h     = ws + OFF_H;
    float* z     = ws + OFF_Z;
    float* hr    = ws + OFF_HR;
    float* sproj = ws + OFF_SP;
    float* tproj = ws + OFF_TP;
    float* out   = (float*)d_out;

    hipMemsetAsync(deg, 0, 512 * sizeof(float), stream);
    hipMemsetAsync(L1d, 0, (size_t)Nn * Nn * sizeof(float), stream);
    hipMemsetAsync(h, 0, (size_t)Bn * NC * sizeof(float), stream);

    k_deg<<<64, 256, 0, stream>>>(ew, esrc, deg);
    k_dinv<<<2, 256, 0, stream>>>(deg, dinv);
    k_nwdense<<<64, 256, 0, stream>>>(ew, esrc, edst, dinv, L1d);
    k_l2<<<64, 256, 0, stream>>>(L1d, L2d);
    k_repack<<<(156032 + 255) / 256, 256, 0, stream>>>(Wx, bx, Wh, bh, W1,
                                                       WzrC, WhC, bzr, bht, W1cat);

    // T1x = L1 @ x ; T2x = L2hat @ x — fused in one dispatch
    k_lmm2<<<Bn * Tn * 8, 256, 0, stream>>>(L1d, L2d, x, T1x, T2x);

    // recurrence: 2 dispatches per GRU cell (launch boundary = the grid barrier)
    for (int t = 0; t < Tn; t++) {
        for (int l = 0; l < Ln; l++) {
            k_cell1<<<512, 256, 0, stream>>>(h, x, T1x, T2x, L1d, L2d,
                                             WzrC + (size_t)l * 384 * 128,
                                             bzr + l * 128, z, hr, t);
            k_cell2<<<512, 256, 0, stream>>>(hr, x, T1x, T2x, L1d, L2d,
                                             WhC + (size_t)l * 384 * 64,
                                             bht + l * 64, z, h, t);
        }
    }

    k_proj<<<128, 256, 0, stream>>>(h, W1cat, b1, sproj, tproj);
    k_logits<<<Bn * 16 * 8, 256, 0, stream>>>(sproj, tproj, W2, b2, out);
}

// Round 7
// 2064.234 us; speedup vs baseline: 24.5042x; 1.0985x over previous
//
#include <hip/hip_runtime.h>

typedef unsigned short ushort;
typedef __attribute__((ext_vector_type(8))) short short8;
typedef __attribute__((ext_vector_type(4))) float f32x4;

// Problem constants
constexpr int Bn = 8, Tn = 16, Nn = 512, Cn = 64, Hn = 64, En = 16384, Ln = 2;
constexpr int NC = Nn * Cn;           // 32768
constexpr int MROWS = Bn * Nn;        // 4096

// ---------------- workspace layout (in floats) ----------------
constexpr size_t OFF_DEG  = 0;
constexpr size_t OFF_DINV = 512;
constexpr size_t OFF_L1D  = 1024;                         // 512*512
constexpr size_t OFF_L2D  = OFF_L1D + 262144;
constexpr size_t OFF_WZR  = OFF_L2D + 262144;             // 2*384*128
constexpr size_t OFF_WHT  = OFF_WZR + 2*384*128;          // 2*384*64
constexpr size_t OFF_BZR  = OFF_WHT + 2*384*64;
constexpr size_t OFF_BHT  = OFF_BZR + 256;
constexpr size_t OFF_W1C  = OFF_BHT + 128;                // 8192
constexpr size_t OFF_T1X  = OFF_W1C + 8192;               // B*T*N*C
constexpr size_t OFF_T2X  = OFF_T1X + (size_t)Bn*Tn*NC;
constexpr size_t OFF_H    = OFF_T2X + (size_t)Bn*Tn*NC;   // B*N*H
constexpr size_t OFF_Z    = OFF_H   + (size_t)Bn*NC;
constexpr size_t OFF_HR   = OFF_Z   + (size_t)Bn*NC;
constexpr size_t OFF_SP   = OFF_HR  + (size_t)Bn*NC;
constexpr size_t OFF_TP   = OFF_SP  + (size_t)MROWS*Hn;
// MFMA support: L-fragments (bf16 hi/lo) + transposed bf16 h/hr (hi/lo)
constexpr size_t OFF_LFH  = OFF_TP  + (size_t)MROWS*Hn;   // 524288 halves = 262144 fl
constexpr size_t OFF_LFL  = OFF_LFH + 262144;
constexpr size_t OFF_HTH  = OFF_LFL + 262144;             // 262144 halves = 131072 fl
constexpr size_t OFF_HTL  = OFF_HTH + 131072;
constexpr size_t OFF_HRTH = OFF_HTL + 131072;
constexpr size_t OFF_HRTL = OFF_HRTH + 131072;
constexpr size_t OFF_END  = OFF_HRTL + 131072;            // ~12.1M fl ~48.4 MB

__device__ __forceinline__ ushort f2bf(float f) {
    unsigned u = __float_as_uint(f);
    u = u + 0x7FFF + ((u >> 16) & 1);
    return (ushort)(u >> 16);
}
__device__ __forceinline__ float bf2f(ushort h) {
    return __uint_as_float(((unsigned)h) << 16);
}

// ---------------- setup kernels ----------------
__global__ void k_deg(const float* __restrict__ w, const int* __restrict__ src,
                      float* __restrict__ deg) {
    int e = blockIdx.x * 256 + threadIdx.x;
    if (e < En) atomicAdd(&deg[src[e]], w[e]);
}

__global__ void k_dinv(const float* __restrict__ deg, float* __restrict__ dinv) {
    int n = blockIdx.x * 256 + threadIdx.x;
    if (n < Nn) {
        float d = deg[n];
        dinv[n] = d > 0.f ? rsqrtf(fmaxf(d, 1e-12f)) : 0.f;
    }
}

__global__ void k_nwdense(const float* __restrict__ w, const int* __restrict__ src,
                          const int* __restrict__ dst, const float* __restrict__ dinv,
                          float* __restrict__ L1d) {
    int e = blockIdx.x * 256 + threadIdx.x;
    if (e < En) {
        int s = src[e], d = dst[e];
        float nw = -w[e] * dinv[s] * dinv[d];
        atomicAdd(&L1d[d * Nn + s], nw);
    }
}

// L2 = 2*(L1@L1) - I
__global__ __launch_bounds__(256) void k_l2(const float* __restrict__ A,
                                            float* __restrict__ C) {
    __shared__ float As[64][33];
    __shared__ float Bs[32][65];
    int t = threadIdx.x;
    int i0 = (blockIdx.x >> 3) * 64;
    int j0 = (blockIdx.x & 7) * 64;
    int tx = t & 15, ty = t >> 4;
    float acc[4][4] = {};
    int ar = t >> 2, ac = (t & 3) * 8;
    int br = t >> 3, bc = (t & 7) * 8;
    for (int kc = 0; kc < 512; kc += 32) {
        float4 a0 = *(const float4*)&A[(size_t)(i0 + ar) * 512 + kc + ac];
        float4 a1 = *(const float4*)&A[(size_t)(i0 + ar) * 512 + kc + ac + 4];
        float4 b0 = *(const float4*)&A[(size_t)(kc + br) * 512 + j0 + bc];
        float4 b1 = *(const float4*)&A[(size_t)(kc + br) * 512 + j0 + bc + 4];
        As[ar][ac+0]=a0.x; As[ar][ac+1]=a0.y; As[ar][ac+2]=a0.z; As[ar][ac+3]=a0.w;
        As[ar][ac+4]=a1.x; As[ar][ac+5]=a1.y; As[ar][ac+6]=a1.z; As[ar][ac+7]=a1.w;
        Bs[br][bc+0]=b0.x; Bs[br][bc+1]=b0.y; Bs[br][bc+2]=b0.z; Bs[br][bc+3]=b0.w;
        Bs[br][bc+4]=b1.x; Bs[br][bc+5]=b1.y; Bs[br][bc+6]=b1.z; Bs[br][bc+7]=b1.w;
        __syncthreads();
#pragma unroll 8
        for (int kk = 0; kk < 32; kk++) {
            float av[4], bv[4];
#pragma unroll
            for (int r = 0; r < 4; r++) av[r] = As[ty * 4 + r][kk];
#pragma unroll
            for (int c = 0; c < 4; c++) bv[c] = Bs[kk][tx * 4 + c];
#pragma unroll
            for (int r = 0; r < 4; r++)
#pragma unroll
                for (int c = 0; c < 4; c++) acc[r][c] += av[r] * bv[c];
        }
        __syncthreads();
    }
#pragma unroll
    for (int r = 0; r < 4; r++)
#pragma unroll
        for (int c = 0; c < 4; c++) {
            int i = i0 + ty * 4 + r, j = j0 + tx * 4 + c;
            C[(size_t)i * 512 + j] = 2.f * acc[r][c] - (i == j ? 1.f : 0.f);
        }
}

// L1/L2 -> bf16 split A-fragments for mfma_f32_16x16x32_bf16.
// layout: idx = ((mat*32+rowblk)*16 + kc)*512 + lane*8 + j
//   row = rowblk*16 + (lane&15); k = kc*32 + (lane>>4)*8 + j
__global__ void k_lfrag(const float* __restrict__ L1, const float* __restrict__ L2,
                        ushort* __restrict__ AfH, ushort* __restrict__ AfL) {
    int idx = blockIdx.x * 256 + threadIdx.x;   // 0..524287
    int j = idx & 7;
    int lane = (idx >> 3) & 63;
    int kc = (idx >> 9) & 15;
    int rb = (idx >> 13) & 31;
    int mat = idx >> 18;
    int row = rb * 16 + (lane & 15);
    int k = kc * 32 + (lane >> 4) * 8 + j;
    float v = (mat ? L2 : L1)[(size_t)row * 512 + k];
    ushort hi = f2bf(v);
    AfH[idx] = hi;
    AfL[idx] = f2bf(v - bf2f(hi));
}

// fused: o1 = L1 @ in[slice], o2 = L2 @ in[slice]
__global__ __launch_bounds__(256) void k_lmm2(const float* __restrict__ L1,
        const float* __restrict__ L2, const float* __restrict__ in,
        float* __restrict__ o1, float* __restrict__ o2) {
    int slice = blockIdx.x >> 3;
    int n0 = (blockIdx.x & 7) * 64;
    const float* xs = in + (size_t)slice * NC;
    float* os1 = o1 + (size_t)slice * NC;
    float* os2 = o2 + (size_t)slice * NC;
    __shared__ float As1[64][33];
    __shared__ float As2[64][33];
    __shared__ float Bs[32][65];
    int t = threadIdx.x;
    int tx = t & 15, ty = t >> 4;
    float acc1[4][4] = {}, acc2[4][4] = {};
    int ar = t >> 2, ac = (t & 3) * 8;
    int br = t >> 3, bc = (t & 7) * 8;
    for (int kc = 0; kc < 512; kc += 32) {
        float4 a0 = *(const float4*)&L1[(size_t)(n0 + ar) * 512 + kc + ac];
        float4 a1 = *(const float4*)&L1[(size_t)(n0 + ar) * 512 + kc + ac + 4];
        float4 c0 = *(const float4*)&L2[(size_t)(n0 + ar) * 512 + kc + ac];
        float4 c1 = *(const float4*)&L2[(size_t)(n0 + ar) * 512 + kc + ac + 4];
        float4 b0 = *(const float4*)&xs[(size_t)(kc + br) * 64 + bc];
        float4 b1 = *(const float4*)&xs[(size_t)(kc + br) * 64 + bc + 4];
        As1[ar][ac+0]=a0.x; As1[ar][ac+1]=a0.y; As1[ar][ac+2]=a0.z; As1[ar][ac+3]=a0.w;
        As1[ar][ac+4]=a1.x; As1[ar][ac+5]=a1.y; As1[ar][ac+6]=a1.z; As1[ar][ac+7]=a1.w;
        As2[ar][ac+0]=c0.x; As2[ar][ac+1]=c0.y; As2[ar][ac+2]=c0.z; As2[ar][ac+3]=c0.w;
        As2[ar][ac+4]=c1.x; As2[ar][ac+5]=c1.y; As2[ar][ac+6]=c1.z; As2[ar][ac+7]=c1.w;
        Bs[br][bc+0]=b0.x; Bs[br][bc+1]=b0.y; Bs[br][bc+2]=b0.z; Bs[br][bc+3]=b0.w;
        Bs[br][bc+4]=b1.x; Bs[br][bc+5]=b1.y; Bs[br][bc+6]=b1.z; Bs[br][bc+7]=b1.w;
        __syncthreads();
#pragma unroll 4
        for (int kk = 0; kk < 32; kk++) {
            float av1[4], av2[4], bv[4];
#pragma unroll
            for (int r = 0; r < 4; r++) { av1[r] = As1[ty*4+r][kk]; av2[r] = As2[ty*4+r][kk]; }
#pragma unroll
            for (int c = 0; c < 4; c++) bv[c] = Bs[kk][tx * 4 + c];
#pragma unroll
            for (int r = 0; r < 4; r++)
#pragma unroll
                for (int c = 0; c < 4; c++) {
                    acc1[r][c] += av1[r] * bv[c];
                    acc2[r][c] += av2[r] * bv[c];
                }
        }
        __syncthreads();
    }
#pragma unroll
    for (int r = 0; r < 4; r++)
#pragma unroll
        for (int c = 0; c < 4; c++) {
            os1[(size_t)(n0 + ty * 4 + r) * 64 + tx * 4 + c] = acc1[r][c];
            os2[(size_t)(n0 + ty * 4 + r) * 64 + tx * 4 + c] = acc2[r][c];
        }
}

// repack weights
__global__ void k_repack(const float* __restrict__ Wx, const float* __restrict__ bx,
                         const float* __restrict__ Wh, const float* __restrict__ bh,
                         const float* __restrict__ W1,
                         float* __restrict__ WzrC, float* __restrict__ WhC,
                         float* __restrict__ bzr, float* __restrict__ bht,
                         float* __restrict__ W1cat) {
    int idx = blockIdx.x * 256 + threadIdx.x;
    if (idx < 98304) {
        int l = idx / 49152, r = idx % 49152;
        int k = r / 128, j = r % 128;
        int g = j >> 6, hh = j & 63;
        int kc, c; const float* s;
        if (k < 192) { kc = k / 64; c = k % 64; s = Wh; }
        else { kc = (k - 192) / 64; c = (k - 192) % 64; s = Wx; }
        WzrC[idx] = s[((((size_t)(l*3 + g))*3 + kc)*64 + c)*64 + hh];
    } else if (idx < 147456) {
        int tI = idx - 98304;
        int l = tI / 24576, r = tI % 24576;
        int k = r / 64, hh = r % 64;
        int kc, c; const float* s;
        if (k < 192) { kc = k / 64; c = k % 64; s = Wh; }
        else { kc = (k - 192) / 64; c = (k - 192) % 64; s = Wx; }
        WhC[tI] = s[((((size_t)(l*3 + 2))*3 + kc)*64 + c)*64 + hh];
    } else if (idx < 147712) {
        int tI = idx - 147456;
        int l = tI >> 7, j = tI & 127;
        int g = j >> 6, hh = j & 63;
        bzr[tI] = bh[(l*3 + g)*64 + hh] + bx[(l*3 + g)*64 + hh];
    } else if (idx < 147840) {
        int tI = idx - 147712;
        int l = tI >> 6, hh = tI & 63;
        bht[tI] = bh[(l*3 + 2)*64 + hh] + bx[(l*3 + 2)*64 + hh];
    } else if (idx < 156032) {
        int tI = idx - 147840;
        int c = tI >> 7, j = tI & 127;
        W1cat[tI] = (j < 64) ? W1[c*64 + j] : W1[(64 + c)*64 + (j - 64)];
    }
}

// ================= cell kernels: 512 blocks x 8 rows =================
// LDS (floats): HT bf16 staging @0 (5120 halves = 2560 fl) | WS@2816 | ASEG@7040 [6][512]
// PRED (phase-B partials) aliases lds[0..2048) after phase A is done.

// Phase A via split-bf16 MFMA: U1 = L1[rows,:]@src, U2 = L2[rows,:]@src.
// A-frags precomputed (constant L). B = src in transposed bf16 hi/lo (hT[c][node]).
// 3 MFMAs per matrix (hi*hi + hi*lo + lo*hi) ~ fp32 precision.
__device__ __forceinline__ void phase_A_mfma(
        float* lds, const ushort* __restrict__ sTh, const ushort* __restrict__ sTl,
        const ushort* __restrict__ AfH, const ushort* __restrict__ AfL,
        int n0, int tid) {
    ushort* HTh = (ushort*)lds;          // [64 feat][40 halves]
    ushort* HTl = HTh + 2560;
    float* U1 = lds + 7040 + 512;
    float* U2 = lds + 7040 + 1024;
    int lane = tid & 63, wav = tid >> 6;
    int quad = lane >> 4, l15 = lane & 15;
    int rowblk = n0 >> 4;
    int srow = tid >> 2, skoff = (tid & 3) * 8;
    size_t ab1 = ((size_t)(0 * 32 + rowblk) * 16) * 512 + lane * 8;
    size_t ab2 = ((size_t)(1 * 32 + rowblk) * 16) * 512 + lane * 8;
    f32x4 acc1 = {0.f, 0.f, 0.f, 0.f}, acc2 = {0.f, 0.f, 0.f, 0.f};
    // prefetch chunk 0
    float4 ph = *(const float4*)&sTh[srow * 512 + skoff];
    float4 pl = *(const float4*)&sTl[srow * 512 + skoff];
    short8 a1h = *(const short8*)&AfH[ab1];
    short8 a1l = *(const short8*)&AfL[ab1];
    short8 a2h = *(const short8*)&AfH[ab2];
    short8 a2l = *(const short8*)&AfL[ab2];
    for (int kc = 0; kc < 16; kc++) {
        __syncthreads();
        *(float4*)&HTh[srow * 40 + skoff] = ph;
        *(float4*)&HTl[srow * 40 + skoff] = pl;
        __syncthreads();
        short8 c1h = a1h, c1l = a1l, c2h = a2h, c2l = a2l;
        if (kc < 15) {
            int kn = kc + 1;
            ph = *(const float4*)&sTh[srow * 512 + kn * 32 + skoff];
            pl = *(const float4*)&sTl[srow * 512 + kn * 32 + skoff];
            a1h = *(const short8*)&AfH[ab1 + (size_t)kn * 512];
            a1l = *(const short8*)&AfL[ab1 + (size_t)kn * 512];
            a2h = *(const short8*)&AfH[ab2 + (size_t)kn * 512];
            a2l = *(const short8*)&AfL[ab2 + (size_t)kn * 512];
        }
        short8 bh = *(const short8*)&HTh[(wav * 16 + l15) * 40 + quad * 8];
        short8 bl = *(const short8*)&HTl[(wav * 16 + l15) * 40 + quad * 8];
        acc1 = __builtin_amdgcn_mfma_f32_16x16x32_bf16(c1h, bh, acc1, 0, 0, 0);
        acc1 = __builtin_amdgcn_mfma_f32_16x16x32_bf16(c1h, bl, acc1, 0, 0, 0);
        acc1 = __builtin_amdgcn_mfma_f32_16x16x32_bf16(c1l, bh, acc1, 0, 0, 0);
        acc2 = __builtin_amdgcn_mfma_f32_16x16x32_bf16(c2h, bh, acc2, 0, 0, 0);
        acc2 = __builtin_amdgcn_mfma_f32_16x16x32_bf16(c2h, bl, acc2, 0, 0, 0);
        acc2 = __builtin_amdgcn_mfma_f32_16x16x32_bf16(c2l, bh, acc2, 0, 0, 0);
    }
    __syncthreads();
    // C layout: row = quad*4+reg, col = wav*16 + l15; keep our 8-row half
    int rbase = n0 & 8;
#pragma unroll
    for (int reg = 0; reg < 4; reg++) {
        int rl = quad * 4 + reg - rbase;
        if (rl >= 0 && rl < 8) {
            U1[rl * 64 + wav * 16 + l15] = acc1[reg];
            U2[rl * 64 + wav * 16 + l15] = acc2[reg];
        }
    }
    __syncthreads();
}

// stage1: z,r = sigmoid(A@Wzr + b); z->global; hr=h*r->global fp32 + bf16 hi/lo transposed
__global__ __launch_bounds__(256) void k_cell1(
        const float* __restrict__ h, const float* __restrict__ x,
        const float* __restrict__ t1x, const float* __restrict__ t2x,
        const ushort* __restrict__ AfH, const ushort* __restrict__ AfL,
        const ushort* __restrict__ hTh, const ushort* __restrict__ hTl,
        const float* __restrict__ W, const float* __restrict__ bias,
        float* __restrict__ z, float* __restrict__ hr,
        ushort* __restrict__ hrTh, ushort* __restrict__ hrTl, int t) {
    __shared__ float lds[10112];
    float* WS   = lds + 2816;
    float* ASEG = lds + 7040;
    float* PRED = lds;
    int tid = threadIdx.x;
    int b = blockIdx.x >> 6;
    int n0 = (blockIdx.x & 63) * 8;
    size_t hoff = ((size_t)b * Nn + n0) * 64;
    size_t xoff = ((size_t)(b * Tn + t) * Nn + n0) * 64;
    {
        int p = tid * 2;
        *(float2*)&ASEG[0 * 512 + p] = *(const float2*)&h[hoff + p];
        *(float2*)&ASEG[3 * 512 + p] = *(const float2*)&x[xoff + p];
        *(float2*)&ASEG[4 * 512 + p] = *(const float2*)&t1x[xoff + p];
        *(float2*)&ASEG[5 * 512 + p] = *(const float2*)&t2x[xoff + p];
    }
    phase_A_mfma(lds, hTh + (size_t)b * 32768, hTl + (size_t)b * 32768, AfH, AfL, n0, tid);

    // phase B1: zr[8][128] = A[8][384] @ W[384][128], fp32, b128 A-reads, k-split-2
    int c4 = tid & 31, rp = (tid >> 5) & 3, kg = tid >> 7;
    int wk = tid >> 3, wc = (tid & 7) * 16;
    float4 pw[4];
#pragma unroll
    for (int q = 0; q < 4; q++)
        pw[q] = *(const float4*)&W[(size_t)wk * 128 + wc + q * 4];
    float acc[2][4] = {};
#pragma unroll
    for (int kt = 0; kt < 12; kt++) {
        __syncthreads();
#pragma unroll
        for (int q = 0; q < 4; q++)
            *(float4*)&WS[wk * 132 + wc + q * 4] = pw[q];
        __syncthreads();
        if (kt < 11) {
#pragma unroll
            for (int q = 0; q < 4; q++)
                pw[q] = *(const float4*)&W[(size_t)((kt + 1) * 32 + wk) * 128 + wc + q * 4];
        }
        const float* S = ASEG + (kt >> 1) * 512;
        int ks0 = (kt & 1) * 32 + kg * 16;
        int wb = kg * 16;
#pragma unroll
        for (int kk4 = 0; kk4 < 4; kk4++) {
            int k4 = kk4 * 4;
            float4 a0 = *(const float4*)&S[(rp * 2 + 0) * 64 + ks0 + k4];
            float4 a1 = *(const float4*)&S[(rp * 2 + 1) * 64 + ks0 + k4];
            float av0[4] = { a0.x, a0.y, a0.z, a0.w };
            float av1[4] = { a1.x, a1.y, a1.z, a1.w };
#pragma unroll
            for (int i = 0; i < 4; i++) {
                float4 wv = *(const float4*)&WS[(wb + k4 + i) * 132 + c4 * 4];
                float wf[4] = { wv.x, wv.y, wv.z, wv.w };
#pragma unroll
                for (int j = 0; j < 4; j++) {
                    acc[0][j] += av0[i] * wf[j];
                    acc[1][j] += av1[i] * wf[j];
                }
            }
        }
    }
    __syncthreads();
#pragma unroll
    for (int rr = 0; rr < 2; rr++)
#pragma unroll
        for (int j = 0; j < 4; j++)
            PRED[kg * 1024 + (rp * 2 + rr) * 128 + c4 * 4 + j] = acc[rr][j];
    __syncthreads();
    for (int i = tid; i < 1024; i += 256) {
        int r = i >> 7, c = i & 127;
        float v = PRED[i] + PRED[1024 + i] + bias[c];
        float s = 1.f / (1.f + __expf(-v));
        size_t grow = ((size_t)(b * Nn + n0 + r)) * 64;
        if (c < 64) {
            z[grow + c] = s;
        } else {
            int c2 = c - 64;
            float hrv = ASEG[r * 64 + c2] * s;
            hr[grow + c2] = hrv;
            ASEG[r * 64 + c2] = hrv;    // stash for transposed bf16 write
        }
    }
    __syncthreads();
    for (int i = tid; i < 512; i += 256) {
        int c = i >> 3, r = i & 7;
        float hrv = ASEG[r * 64 + c];
        size_t gi = (size_t)b * 32768 + (size_t)c * 512 + n0 + r;
        ushort hi = f2bf(hrv);
        hrTh[gi] = hi;
        hrTl[gi] = f2bf(hrv - bf2f(hi));
    }
}

// stage2: ht = tanh(A@Wht + b); h = z*h + (1-z)*ht -> global fp32 + bf16 hi/lo transposed
__global__ __launch_bounds__(256) void k_cell2(
        const float* __restrict__ hrp, const float* __restrict__ x,
        const float* __restrict__ t1x, const float* __restrict__ t2x,
        const ushort* __restrict__ AfH, const ushort* __restrict__ AfL,
        const ushort* __restrict__ hrTh, const ushort* __restrict__ hrTl,
        const float* __restrict__ W, const float* __restrict__ bias,
        const float* __restrict__ z, float* __restrict__ h,
        ushort* __restrict__ hTh, ushort* __restrict__ hTl, int t) {
    __shared__ float lds[10112];
    float* WS   = lds + 2816;
    float* ASEG = lds + 7040;
    float* PRED = lds;
    int tid = threadIdx.x;
    int b = blockIdx.x >> 6;
    int n0 = (blockIdx.x & 63) * 8;
    size_t hoff = ((size_t)b * Nn + n0) * 64;
    size_t xoff = ((size_t)(b * Tn + t) * Nn + n0) * 64;
    {
        int p = tid * 2;
        *(float2*)&ASEG[0 * 512 + p] = *(const float2*)&hrp[hoff + p];
        *(float2*)&ASEG[3 * 512 + p] = *(const float2*)&x[xoff + p];
        *(float2*)&ASEG[4 * 512 + p] = *(const float2*)&t1x[xoff + p];
        *(float2*)&ASEG[5 * 512 + p] = *(const float2*)&t2x[xoff + p];
    }
    phase_A_mfma(lds, hrTh + (size_t)b * 32768, hrTl + (size_t)b * 32768, AfH, AfL, n0, tid);

    // phase B2: ht[8][64] = A[8][384] @ W[384][64], fp32, b128 A-reads, k-split-4
    int c4 = tid & 15, rp = (tid >> 4) & 3, kg = tid >> 6;
    int wk = tid >> 3, wc = (tid & 7) * 8;
    float4 pw0 = *(const float4*)&W[(size_t)wk * 64 + wc];
    float4 pw1 = *(const float4*)&W[(size_t)wk * 64 + wc + 4];
    float acc[2][4] = {};
#pragma unroll
    for (int kt = 0; kt < 12; kt++) {
        __syncthreads();
        *(float4*)&WS[wk * 68 + wc] = pw0;
        *(float4*)&WS[wk * 68 + wc + 4] = pw1;
        __syncthreads();
        if (kt < 11) {
            pw0 = *(const float4*)&W[(size_t)((kt + 1) * 32 + wk) * 64 + wc];
            pw1 = *(const float4*)&W[(size_t)((kt + 1) * 32 + wk) * 64 + wc + 4];
        }
        const float* S = ASEG + (kt >> 1) * 512;
        int ks0 = (kt & 1) * 32 + kg * 8;
        int wb = kg * 8;
#pragma unroll
        for (int kk4 = 0; kk4 < 2; kk4++) {
            int k4 = kk4 * 4;
            float4 a0 = *(const float4*)&S[(rp * 2 + 0) * 64 + ks0 + k4];
            float4 a1 = *(const float4*)&S[(rp * 2 + 1) * 64 + ks0 + k4];
            float av0[4] = { a0.x, a0.y, a0.z, a0.w };
            float av1[4] = { a1.x, a1.y, a1.z, a1.w };
#pragma unroll
            for (int i = 0; i < 4; i++) {
                float4 wv = *(const float4*)&WS[(wb + k4 + i) * 68 + c4 * 4];
                float wf[4] = { wv.x, wv.y, wv.z, wv.w };
#pragma unroll
                for (int j = 0; j < 4; j++) {
                    acc[0][j] += av0[i] * wf[j];
                    acc[1][j] += av1[i] * wf[j];
                }
            }
        }
    }
    __syncthreads();
#pragma unroll
    for (int rr = 0; rr < 2; rr++)
#pragma unroll
        for (int j = 0; j < 4; j++)
            PRED[kg * 512 + (rp * 2 + rr) * 64 + c4 * 4 + j] = acc[rr][j];
    __syncthreads();
    for (int i = tid; i < 512; i += 256) {
        int r = i >> 6, c = i & 63;
        float v = PRED[i] + PRED[512 + i] + PRED[1024 + i] + PRED[1536 + i] + bias[c];
        float ht = tanhf(v);
        size_t p = ((size_t)(b * Nn + n0 + r)) * 64 + c;
        float zz = z[p], hold = h[p];
        float hn = zz * hold + (1.f - zz) * ht;
        h[p] = hn;
        ASEG[r * 64 + c] = hn;          // stash for transposed bf16 write
    }
    __syncthreads();
    for (int i = tid; i < 512; i += 256) {
        int c = i >> 3, r = i & 7;
        float hn = ASEG[r * 64 + c];
        size_t gi = (size_t)b * 32768 + (size_t)c * 512 + n0 + r;
        ushort hi = f2bf(hn);
        hTh[gi] = hi;
        hTl[gi] = f2bf(hn - bf2f(hi));
    }
}

// ---------------- projections ----------------
__global__ __launch_bounds__(256) void k_proj(
        const float* __restrict__ h, const float* __restrict__ W1cat,
        const float* __restrict__ b1,
        float* __restrict__ sproj, float* __restrict__ tproj) {
    __shared__ float As[16][33];
    __shared__ float Ws[16 * 128];
    int tid = threadIdx.x;
    int row0 = blockIdx.x * 32;
    const float* hp = h + (size_t)row0 * 64;
    float acc[2][8] = {};
    int tx = tid & 15, ty = tid >> 4;
    int lr = tid >> 3;
    int lk = (tid & 7) * 2;
    int wk = tid >> 4;
    int wc = (tid & 15) * 8;
    for (int kt = 0; kt < 4; kt++) {
        int c0 = kt * 16;
        float2 a2 = *(const float2*)&hp[lr * 64 + c0 + lk];
        const float4* wsrc = (const float4*)&W1cat[(size_t)(kt * 16 + wk) * 128 + wc];
        float4 w0 = wsrc[0], w1 = wsrc[1];
        As[lk][lr] = a2.x;
        As[lk + 1][lr] = a2.y;
        *(float4*)&Ws[wk * 128 + wc] = w0;
        *(float4*)&Ws[wk * 128 + wc + 4] = w1;
        __syncthreads();
#pragma unroll
        for (int kk = 0; kk < 16; kk++) {
            float a0 = As[kk][ty * 2 + 0];
            float a1 = As[kk][ty * 2 + 1];
            float4 p0 = *(const float4*)&Ws[kk * 128 + tx * 8];
            float4 p1 = *(const float4*)&Ws[kk * 128 + tx * 8 + 4];
            float w[8] = { p0.x, p0.y, p0.z, p0.w, p1.x, p1.y, p1.z, p1.w };
#pragma unroll
            for (int cc = 0; cc < 8; cc++) {
                acc[0][cc] += a0 * w[cc];
                acc[1][cc] += a1 * w[cc];
            }
        }
        __syncthreads();
    }
#pragma unroll
    for (int rr = 0; rr < 2; rr++) {
        int row = row0 + ty * 2 + rr;
#pragma unroll
        for (int cc = 0; cc < 8; cc++) {
            int col = tx * 8 + cc;
            float v = acc[rr][cc];
            if (col < 64) sproj[(size_t)row * 64 + col] = v + b1[col];
            else tproj[(size_t)row * 64 + (col - 64)] = v;
        }
    }
}

// ---------------- logits ----------------
__global__ __launch_bounds__(256) void k_logits(
        const float* __restrict__ sproj, const float* __restrict__ tproj,
        const float* __restrict__ W2, const float* __restrict__ b2,
        float* __restrict__ out) {
    __shared__ float sp[32 * 64];
    __shared__ float tp[64 * 65];
    __shared__ float w2s[64];
    int tid = threadIdx.x;
    int bb = blockIdx.x >> 7;
    int st = (blockIdx.x >> 3) & 15;
    int tt = blockIdx.x & 7;
    const float* spg = sproj + ((size_t)bb * Nn + st * 32) * 64;
    const float* tpg = tproj + ((size_t)bb * Nn + tt * 64) * 64;
    for (int i = tid; i < 2048; i += 256) sp[i] = spg[i];
    for (int i = tid; i < 4096; i += 256) {
        int tl = i >> 6, hh = i & 63;
        tp[tl * 65 + hh] = tpg[i];
    }
    if (tid < 64) w2s[tid] = W2[tid];
    __syncthreads();
    float bias = *b2;
    int tl = tid & 63, sg = tid >> 6;
    for (int si = 0; si < 8; si++) {
        int s = sg * 8 + si;
        float acc = bias;
#pragma unroll 8
        for (int hh = 0; hh < 64; hh++) {
            float v = sp[s * 64 + hh] + tp[tl * 65 + hh];
            acc += fmaxf(v, 0.f) * w2s[hh];
        }
        out[(size_t)bb * Nn * Nn + (size_t)(st * 32 + s) * Nn + tt * 64 + tl] = acc;
    }
}

// ---------------- host ----------------
extern "C" void kernel_launch(void* const* d_in, const int* in_sizes, int n_in,
                              void* d_out, int out_size, void* d_ws, size_t ws_size,
                              hipStream_t stream) {
    const float* x  = (const float*)d_in[0];
    const float* ew = (const float*)d_in[1];
    const float* Wx = (const float*)d_in[2];
    const float* bx = (const float*)d_in[3];
    const float* Wh = (const float*)d_in[4];
    const float* bh = (const float*)d_in[5];
    const float* W1 = (const float*)d_in[6];
    const float* b1 = (const float*)d_in[7];
    const float* W2 = (const float*)d_in[8];
    const float* b2 = (const float*)d_in[9];
    const int* ei   = (const int*)d_in[10];
    const int* esrc = ei;
    const int* edst = ei + En;

    float* ws = (float*)d_ws;
    float* deg   = ws + OFF_DEG;
    float* dinv  = ws + OFF_DINV;
    float* L1d   = ws + OFF_L1D;
    float* L2d   = ws + OFF_L2D;
    float* WzrC  = ws + OFF_WZR;
    float* WhC   = ws + OFF_WHT;
    float* bzr   = ws + OFF_BZR;
    float* bht   = ws + OFF_BHT;
    float* W1cat = ws + OFF_W1C;
    float* T1x   = ws + OFF_T1X;
    float* T2x   = ws + OFF_T2X;
    float* h     = ws + OFF_H;
    float* z     = ws + OFF_Z;
    float* hr    = ws + OFF_HR;
    float* sproj = ws + OFF_SP;
    float* tproj = ws + OFF_TP;
    ushort* AfH  = (ushort*)(ws + OFF_LFH);
    ushort* AfL  = (ushort*)(ws + OFF_LFL);
    ushort* hTh  = (ushort*)(ws + OFF_HTH);
    ushort* hTl  = (ushort*)(ws + OFF_HTL);
    ushort* hrTh = (ushort*)(ws + OFF_HRTH);
    ushort* hrTl = (ushort*)(ws + OFF_HRTL);
    float* out   = (float*)d_out;

    hipMemsetAsync(deg, 0, 512 * sizeof(float), stream);
    hipMemsetAsync(L1d, 0, (size_t)Nn * Nn * sizeof(float), stream);
    hipMemsetAsync(h, 0, (size_t)Bn * NC * sizeof(float), stream);
    hipMemsetAsync(hTh, 0, 262144 * sizeof(ushort), stream);
    hipMemsetAsync(hTl, 0, 262144 * sizeof(ushort), stream);

    k_deg<<<64, 256, 0, stream>>>(ew, esrc, deg);
    k_dinv<<<2, 256, 0, stream>>>(deg, dinv);
    k_nwdense<<<64, 256, 0, stream>>>(ew, esrc, edst, dinv, L1d);
    k_l2<<<64, 256, 0, stream>>>(L1d, L2d);
    k_lfrag<<<2048, 256, 0, stream>>>(L1d, L2d, AfH, AfL);
    k_repack<<<(156032 + 255) / 256, 256, 0, stream>>>(Wx, bx, Wh, bh, W1,
                                                       WzrC, WhC, bzr, bht, W1cat);

    k_lmm2<<<Bn * Tn * 8, 256, 0, stream>>>(L1d, L2d, x, T1x, T2x);

    for (int t = 0; t < Tn; t++) {
        for (int l = 0; l < Ln; l++) {
            k_cell1<<<512, 256, 0, stream>>>(h, x, T1x, T2x, AfH, AfL, hTh, hTl,
                                             WzrC + (size_t)l * 384 * 128,
                                             bzr + l * 128, z, hr, hrTh, hrTl, t);
            k_cell2<<<512, 256, 0, stream>>>(hr, x, T1x, T2x, AfH, AfL, hrTh, hrTl,
                                             WhC + (size_t)l * 384 * 64,
                                             bht + l * 64, z, h, hTh, hTl, t);
        }
    }

    k_proj<<<128, 256, 0, stream>>>(h, W1cat, b1, sproj, tproj);
    k_logits<<<Bn * 16 * 8, 256, 0, stream>>>(sproj, tproj, W2, b2, out);
}

// Round 8
// 1169.707 us; speedup vs baseline: 43.2437x; 1.7647x over previous
//
#include <hip/hip_runtime.h>

typedef unsigned short ushort;
typedef __attribute__((ext_vector_type(8))) short short8;
typedef __attribute__((ext_vector_type(4))) float f32x4;

// Problem constants
constexpr int Bn = 8, Tn = 16, Nn = 512, Cn = 64, Hn = 64, En = 16384, Ln = 2;
constexpr int NC = Nn * Cn;           // 32768
constexpr int MROWS = Bn * Nn;        // 4096

// ---------------- workspace layout (in floats) ----------------
constexpr size_t OFF_DEG  = 0;
constexpr size_t OFF_DINV = 512;
constexpr size_t OFF_L1D  = 1024;                         // 512*512
constexpr size_t OFF_L2D  = OFF_L1D + 262144;
constexpr size_t OFF_WZR  = OFF_L2D + 262144;             // 2*384*128
constexpr size_t OFF_WHT  = OFF_WZR + 2*384*128;          // 2*384*64
constexpr size_t OFF_BZR  = OFF_WHT + 2*384*64;
constexpr size_t OFF_BHT  = OFF_BZR + 256;
constexpr size_t OFF_W1C  = OFF_BHT + 128;                // 8192
constexpr size_t OFF_T1X  = OFF_W1C + 8192;               // B*T*N*C
constexpr size_t OFF_T2X  = OFF_T1X + (size_t)Bn*Tn*NC;
constexpr size_t OFF_H    = OFF_T2X + (size_t)Bn*Tn*NC;   // B*N*H
constexpr size_t OFF_Z    = OFF_H   + (size_t)Bn*NC;
constexpr size_t OFF_HR   = OFF_Z   + (size_t)Bn*NC;
constexpr size_t OFF_SP   = OFF_HR  + (size_t)Bn*NC;      // sproj; W-frags alias this
constexpr size_t OFF_TP   = OFF_SP  + (size_t)MROWS*Hn;   //   (recurrence-only lifetime)
constexpr size_t OFF_LFH  = OFF_TP  + (size_t)MROWS*Hn;   // L-frags bf16 hi/lo
constexpr size_t OFF_LFL  = OFF_LFH + 262144;
constexpr size_t OFF_HTH  = OFF_LFL + 262144;             // transposed bf16 h/hr hi/lo
constexpr size_t OFF_HTL  = OFF_HTH + 131072;
constexpr size_t OFF_HRTH = OFF_HTL + 131072;
constexpr size_t OFF_HRTL = OFF_HRTH + 131072;
constexpr size_t OFF_END  = OFF_HRTL + 131072;

__device__ __forceinline__ ushort f2bf(float f) {
    unsigned u = __float_as_uint(f);
    u = u + 0x7FFF + ((u >> 16) & 1);
    return (ushort)(u >> 16);
}
__device__ __forceinline__ float bf2f(ushort h) {
    return __uint_as_float(((unsigned)h) << 16);
}
// fragment-linear LDS layout for a 16x64 bf16 A-operand panel:
// value (m,k) lives at (k>>5)*512 + ((k>>3)&3)*128 + m*8 + (k&7)
__device__ __forceinline__ int fragaddr(int m, int k) {
    return ((k >> 5) << 9) + (((k >> 3) & 3) << 7) + (m << 3) + (k & 7);
}

// ---------------- setup kernels ----------------
__global__ void k_deg(const float* __restrict__ w, const int* __restrict__ src,
                      float* __restrict__ deg) {
    int e = blockIdx.x * 256 + threadIdx.x;
    if (e < En) atomicAdd(&deg[src[e]], w[e]);
}

__global__ void k_dinv(const float* __restrict__ deg, float* __restrict__ dinv) {
    int n = blockIdx.x * 256 + threadIdx.x;
    if (n < Nn) {
        float d = deg[n];
        dinv[n] = d > 0.f ? rsqrtf(fmaxf(d, 1e-12f)) : 0.f;
    }
}

__global__ void k_nwdense(const float* __restrict__ w, const int* __restrict__ src,
                          const int* __restrict__ dst, const float* __restrict__ dinv,
                          float* __restrict__ L1d) {
    int e = blockIdx.x * 256 + threadIdx.x;
    if (e < En) {
        int s = src[e], d = dst[e];
        float nw = -w[e] * dinv[s] * dinv[d];
        atomicAdd(&L1d[d * Nn + s], nw);
    }
}

// L2 = 2*(L1@L1) - I
__global__ __launch_bounds__(256) void k_l2(const float* __restrict__ A,
                                            float* __restrict__ C) {
    __shared__ float As[64][33];
    __shared__ float Bs[32][65];
    int t = threadIdx.x;
    int i0 = (blockIdx.x >> 3) * 64;
    int j0 = (blockIdx.x & 7) * 64;
    int tx = t & 15, ty = t >> 4;
    float acc[4][4] = {};
    int ar = t >> 2, ac = (t & 3) * 8;
    int br = t >> 3, bc = (t & 7) * 8;
    for (int kc = 0; kc < 512; kc += 32) {
        float4 a0 = *(const float4*)&A[(size_t)(i0 + ar) * 512 + kc + ac];
        float4 a1 = *(const float4*)&A[(size_t)(i0 + ar) * 512 + kc + ac + 4];
        float4 b0 = *(const float4*)&A[(size_t)(kc + br) * 512 + j0 + bc];
        float4 b1 = *(const float4*)&A[(size_t)(kc + br) * 512 + j0 + bc + 4];
        As[ar][ac+0]=a0.x; As[ar][ac+1]=a0.y; As[ar][ac+2]=a0.z; As[ar][ac+3]=a0.w;
        As[ar][ac+4]=a1.x; As[ar][ac+5]=a1.y; As[ar][ac+6]=a1.z; As[ar][ac+7]=a1.w;
        Bs[br][bc+0]=b0.x; Bs[br][bc+1]=b0.y; Bs[br][bc+2]=b0.z; Bs[br][bc+3]=b0.w;
        Bs[br][bc+4]=b1.x; Bs[br][bc+5]=b1.y; Bs[br][bc+6]=b1.z; Bs[br][bc+7]=b1.w;
        __syncthreads();
#pragma unroll 8
        for (int kk = 0; kk < 32; kk++) {
            float av[4], bv[4];
#pragma unroll
            for (int r = 0; r < 4; r++) av[r] = As[ty * 4 + r][kk];
#pragma unroll
            for (int c = 0; c < 4; c++) bv[c] = Bs[kk][tx * 4 + c];
#pragma unroll
            for (int r = 0; r < 4; r++)
#pragma unroll
                for (int c = 0; c < 4; c++) acc[r][c] += av[r] * bv[c];
        }
        __syncthreads();
    }
#pragma unroll
    for (int r = 0; r < 4; r++)
#pragma unroll
        for (int c = 0; c < 4; c++) {
            int i = i0 + ty * 4 + r, j = j0 + tx * 4 + c;
            C[(size_t)i * 512 + j] = 2.f * acc[r][c] - (i == j ? 1.f : 0.f);
        }
}

// L1/L2 -> bf16 split A-fragments; idx = ((mat*32+rb)*16 + kc)*512 + lane*8 + j
__global__ void k_lfrag(const float* __restrict__ L1, const float* __restrict__ L2,
                        ushort* __restrict__ AfH, ushort* __restrict__ AfL) {
    int idx = blockIdx.x * 256 + threadIdx.x;   // 0..524287
    int j = idx & 7;
    int lane = (idx >> 3) & 63;
    int kc = (idx >> 9) & 15;
    int rb = (idx >> 13) & 31;
    int mat = idx >> 18;
    int row = rb * 16 + (lane & 15);
    int k = kc * 32 + (lane >> 4) * 8 + j;
    float v = (mat ? L2 : L1)[(size_t)row * 512 + k];
    ushort hi = f2bf(v);
    AfH[idx] = hi;
    AfL[idx] = f2bf(v - bf2f(hi));
}

// Wzr/Wht -> bf16 split B-fragments: idx = ((l*CT + ct)*12 + kc)*512 + lane*8 + j
//   n = ct*16 + (lane&15), k = kc*32 + (lane>>4)*8 + j
__global__ void k_wfrag(const float* __restrict__ WzrC, const float* __restrict__ WhC,
                        ushort* __restrict__ WzFH, ushort* __restrict__ WzFL,
                        ushort* __restrict__ WhFH, ushort* __restrict__ WhFL) {
    int idx = blockIdx.x * 256 + threadIdx.x;
    if (idx < 98304) {
        int l = idx / 49152, off = idx % 49152;
        int tile = off >> 9, r = off & 511;
        int lane = r >> 3, j = r & 7;
        int ct = tile / 12, kc = tile % 12;
        int k = kc * 32 + (lane >> 4) * 8 + j;
        int n = ct * 16 + (lane & 15);
        float v = WzrC[(size_t)l * 49152 + k * 128 + n];
        ushort hi = f2bf(v);
        WzFH[idx] = hi;
        WzFL[idx] = f2bf(v - bf2f(hi));
    } else if (idx < 147456) {
        int t2 = idx - 98304;
        int l = t2 / 24576, off = t2 % 24576;
        int tile = off >> 9, r = off & 511;
        int lane = r >> 3, j = r & 7;
        int ct = tile / 12, kc = tile % 12;
        int k = kc * 32 + (lane >> 4) * 8 + j;
        int n = ct * 16 + (lane & 15);
        float v = WhC[(size_t)l * 24576 + k * 64 + n];
        ushort hi = f2bf(v);
        WhFH[t2] = hi;
        WhFL[t2] = f2bf(v - bf2f(hi));
    }
}

// fused: o1 = L1 @ in[slice], o2 = L2 @ in[slice]
__global__ __launch_bounds__(256) void k_lmm2(const float* __restrict__ L1,
        const float* __restrict__ L2, const float* __restrict__ in,
        float* __restrict__ o1, float* __restrict__ o2) {
    int slice = blockIdx.x >> 3;
    int n0 = (blockIdx.x & 7) * 64;
    const float* xs = in + (size_t)slice * NC;
    float* os1 = o1 + (size_t)slice * NC;
    float* os2 = o2 + (size_t)slice * NC;
    __shared__ float As1[64][33];
    __shared__ float As2[64][33];
    __shared__ float Bs[32][65];
    int t = threadIdx.x;
    int tx = t & 15, ty = t >> 4;
    float acc1[4][4] = {}, acc2[4][4] = {};
    int ar = t >> 2, ac = (t & 3) * 8;
    int br = t >> 3, bc = (t & 7) * 8;
    for (int kc = 0; kc < 512; kc += 32) {
        float4 a0 = *(const float4*)&L1[(size_t)(n0 + ar) * 512 + kc + ac];
        float4 a1 = *(const float4*)&L1[(size_t)(n0 + ar) * 512 + kc + ac + 4];
        float4 c0 = *(const float4*)&L2[(size_t)(n0 + ar) * 512 + kc + ac];
        float4 c1 = *(const float4*)&L2[(size_t)(n0 + ar) * 512 + kc + ac + 4];
        float4 b0 = *(const float4*)&xs[(size_t)(kc + br) * 64 + bc];
        float4 b1 = *(const float4*)&xs[(size_t)(kc + br) * 64 + bc + 4];
        As1[ar][ac+0]=a0.x; As1[ar][ac+1]=a0.y; As1[ar][ac+2]=a0.z; As1[ar][ac+3]=a0.w;
        As1[ar][ac+4]=a1.x; As1[ar][ac+5]=a1.y; As1[ar][ac+6]=a1.z; As1[ar][ac+7]=a1.w;
        As2[ar][ac+0]=c0.x; As2[ar][ac+1]=c0.y; As2[ar][ac+2]=c0.z; As2[ar][ac+3]=c0.w;
        As2[ar][ac+4]=c1.x; As2[ar][ac+5]=c1.y; As2[ar][ac+6]=c1.z; As2[ar][ac+7]=c1.w;
        Bs[br][bc+0]=b0.x; Bs[br][bc+1]=b0.y; Bs[br][bc+2]=b0.z; Bs[br][bc+3]=b0.w;
        Bs[br][bc+4]=b1.x; Bs[br][bc+5]=b1.y; Bs[br][bc+6]=b1.z; Bs[br][bc+7]=b1.w;
        __syncthreads();
#pragma unroll 4
        for (int kk = 0; kk < 32; kk++) {
            float av1[4], av2[4], bv[4];
#pragma unroll
            for (int r = 0; r < 4; r++) { av1[r] = As1[ty*4+r][kk]; av2[r] = As2[ty*4+r][kk]; }
#pragma unroll
            for (int c = 0; c < 4; c++) bv[c] = Bs[kk][tx * 4 + c];
#pragma unroll
            for (int r = 0; r < 4; r++)
#pragma unroll
                for (int c = 0; c < 4; c++) {
                    acc1[r][c] += av1[r] * bv[c];
                    acc2[r][c] += av2[r] * bv[c];
                }
        }
        __syncthreads();
    }
#pragma unroll
    for (int r = 0; r < 4; r++)
#pragma unroll
        for (int c = 0; c < 4; c++) {
            os1[(size_t)(n0 + ty * 4 + r) * 64 + tx * 4 + c] = acc1[r][c];
            os2[(size_t)(n0 + ty * 4 + r) * 64 + tx * 4 + c] = acc2[r][c];
        }
}

// repack weights
__global__ void k_repack(const float* __restrict__ Wx, const float* __restrict__ bx,
                         const float* __restrict__ Wh, const float* __restrict__ bh,
                         const float* __restrict__ W1,
                         float* __restrict__ WzrC, float* __restrict__ WhC,
                         float* __restrict__ bzr, float* __restrict__ bht,
                         float* __restrict__ W1cat) {
    int idx = blockIdx.x * 256 + threadIdx.x;
    if (idx < 98304) {
        int l = idx / 49152, r = idx % 49152;
        int k = r / 128, j = r % 128;
        int g = j >> 6, hh = j & 63;
        int kc, c; const float* s;
        if (k < 192) { kc = k / 64; c = k % 64; s = Wh; }
        else { kc = (k - 192) / 64; c = (k - 192) % 64; s = Wx; }
        WzrC[idx] = s[((((size_t)(l*3 + g))*3 + kc)*64 + c)*64 + hh];
    } else if (idx < 147456) {
        int tI = idx - 98304;
        int l = tI / 24576, r = tI % 24576;
        int k = r / 64, hh = r % 64;
        int kc, c; const float* s;
        if (k < 192) { kc = k / 64; c = k % 64; s = Wh; }
        else { kc = (k - 192) / 64; c = (k - 192) % 64; s = Wx; }
        WhC[tI] = s[((((size_t)(l*3 + 2))*3 + kc)*64 + c)*64 + hh];
    } else if (idx < 147712) {
        int tI = idx - 147456;
        int l = tI >> 7, j = tI & 127;
        int g = j >> 6, hh = j & 63;
        bzr[tI] = bh[(l*3 + g)*64 + hh] + bx[(l*3 + g)*64 + hh];
    } else if (idx < 147840) {
        int tI = idx - 147712;
        int l = tI >> 6, hh = tI & 63;
        bht[tI] = bh[(l*3 + 2)*64 + hh] + bx[(l*3 + 2)*64 + hh];
    } else if (idx < 156032) {
        int tI = idx - 147840;
        int c = tI >> 7, j = tI & 127;
        W1cat[tI] = (j < 64) ? W1[c*64 + j] : W1[(64 + c)*64 + (j - 64)];
    }
}

// ================= full-MFMA cell kernels: 256 blocks x 16 rows =================
// LDS (floats): AH@0 (6x1024 halves = 3072 fl) | AL@3072 | PRED@6144 (2048) | HRS@8192 (1024)
// segs: 0 = h/hr, 1 = U1, 2 = U2, 3 = x, 4 = t1x, 5 = t2x — all bf16 hi/lo, frag-linear.
// 3 barriers per kernel (vs ~50 in the fp32 version).

#define MFMA16(a, b, c) __builtin_amdgcn_mfma_f32_16x16x32_bf16((a), (b), (c), 0, 0, 0)

// common: stage segs 0,3,4,5 (fp32 global -> bf16 hi/lo frags)
__device__ __forceinline__ void stage_segs(
        ushort* AH, ushort* AL, const float* s0, const float* x,
        const float* t1x, const float* t2x, size_t xoff, int tid) {
    int p = tid * 4;
    int m = p >> 6, kb = p & 63;
    int fa = fragaddr(m, kb);
    const float* srcs[4] = { s0, x + xoff, t1x + xoff, t2x + xoff };
    const int sidx[4] = { 0, 3, 4, 5 };
#pragma unroll
    for (int q = 0; q < 4; q++) {
        float4 v = *(const float4*)&srcs[q][(size_t)m * 64 + kb];
        float vv[4] = { v.x, v.y, v.z, v.w };
        int base = sidx[q] * 1024 + fa;
#pragma unroll
        for (int j = 0; j < 4; j++) {
            ushort hi = f2bf(vv[j]);
            AH[base + j] = hi;
            AL[base + j] = f2bf(vv[j] - bf2f(hi));
        }
    }
}

// phase A: U1 = L1[rows,:]@src, U2 = L2[rows,:]@src (M=16,N=64,K=512) via split-bf16 MFMA.
// A-frags from global (constant L), B-frags from transposed bf16 src — no LDS in loop.
__device__ __forceinline__ void phase_A16(
        ushort* AH, ushort* AL,
        const ushort* __restrict__ sTh, const ushort* __restrict__ sTl,
        const ushort* __restrict__ AfH, const ushort* __restrict__ AfL,
        int rowblk, int tid) {
    int lane = tid & 63, wav = tid >> 6;
    int quad = lane >> 4, l15 = lane & 15;
    size_t ab1 = ((size_t)rowblk * 16) * 512 + lane * 8;
    size_t ab2 = ((size_t)(32 + rowblk) * 16) * 512 + lane * 8;
    size_t bb = (size_t)(wav * 16 + l15) * 512 + quad * 8;
    f32x4 acc1 = {0.f,0.f,0.f,0.f}, acc2 = {0.f,0.f,0.f,0.f};
    short8 a1h = *(const short8*)&AfH[ab1];
    short8 a1l = *(const short8*)&AfL[ab1];
    short8 a2h = *(const short8*)&AfH[ab2];
    short8 a2l = *(const short8*)&AfL[ab2];
    short8 bh  = *(const short8*)&sTh[bb];
    short8 bl  = *(const short8*)&sTl[bb];
    for (int kc = 0; kc < 16; kc++) {
        short8 c1h = a1h, c1l = a1l, c2h = a2h, c2l = a2l, dh = bh, dl = bl;
        if (kc < 15) {
            size_t o = (size_t)(kc + 1) * 512;
            a1h = *(const short8*)&AfH[ab1 + o];
            a1l = *(const short8*)&AfL[ab1 + o];
            a2h = *(const short8*)&AfH[ab2 + o];
            a2l = *(const short8*)&AfL[ab2 + o];
            bh = *(const short8*)&sTh[bb + (kc + 1) * 32];
            bl = *(const short8*)&sTl[bb + (kc + 1) * 32];
        }
        acc1 = MFMA16(c1h, dh, acc1);
        acc1 = MFMA16(c1h, dl, acc1);
        acc1 = MFMA16(c1l, dh, acc1);
        acc2 = MFMA16(c2h, dh, acc2);
        acc2 = MFMA16(c2h, dl, acc2);
        acc2 = MFMA16(c2l, dh, acc2);
    }
    int colA = wav * 16 + l15;
#pragma unroll
    for (int reg = 0; reg < 4; reg++) {
        int row = quad * 4 + reg;
        float u1 = acc1[reg], u2 = acc2[reg];
        ushort h1 = f2bf(u1), h2 = f2bf(u2);
        int fa1 = 1024 + fragaddr(row, colA);
        int fa2 = 2048 + fragaddr(row, colA);
        AH[fa1] = h1; AL[fa1] = f2bf(u1 - bf2f(h1));
        AH[fa2] = h2; AL[fa2] = f2bf(u2 - bf2f(h2));
    }
}

// stage1: z,r = sigmoid(A@Wzr + b); z->global; hr = h*r -> global fp32 + bf16 transposed
__global__ __launch_bounds__(256) void k_cell1(
        const float* __restrict__ h, const float* __restrict__ x,
        const float* __restrict__ t1x, const float* __restrict__ t2x,
        const ushort* __restrict__ AfH, const ushort* __restrict__ AfL,
        const ushort* __restrict__ hTh, const ushort* __restrict__ hTl,
        const ushort* __restrict__ WFH, const ushort* __restrict__ WFL,
        const float* __restrict__ bias,
        float* __restrict__ z, float* __restrict__ hr,
        ushort* __restrict__ hrTh, ushort* __restrict__ hrTl, int t) {
    __shared__ float lds[9216];
    ushort* AH = (ushort*)lds;
    ushort* AL = (ushort*)(lds + 3072);
    float* PRED = lds + 6144;
    float* HRS  = lds + 8192;
    int tid = threadIdx.x;
    int b = blockIdx.x >> 5;
    int rowblk = blockIdx.x & 31;
    int n0 = rowblk * 16;
    size_t hoff = ((size_t)b * Nn + n0) * 64;
    size_t xoff = ((size_t)(b * Tn + t) * Nn + n0) * 64;

    stage_segs(AH, AL, h + hoff, x, t1x, t2x, xoff, tid);
    phase_A16(AH, AL, hTh + (size_t)b * 32768, hTl + (size_t)b * 32768,
              AfH, AfL, rowblk, tid);
    __syncthreads();

    // phase B1: zr[16][128] = A[16][384] @ Wzr — MFMA, 2 col-passes/wave
    int lane = tid & 63, wav = tid >> 6;
    int quad = lane >> 4, l15 = lane & 15;
    {
        int abase = quad * 128 + l15 * 8;
        size_t w0 = ((size_t)wav * 12) * 512 + lane * 8;        // ct = wav    (z cols)
        size_t w1 = ((size_t)(4 + wav) * 12) * 512 + lane * 8;  // ct = 4+wav  (r cols)
        f32x4 acc0 = {0.f,0.f,0.f,0.f}, acc1v = {0.f,0.f,0.f,0.f};
        short8 ah = *(const short8*)&AH[abase];
        short8 al = *(const short8*)&AL[abase];
        short8 w0h = *(const short8*)&WFH[w0];
        short8 w0l = *(const short8*)&WFL[w0];
        short8 w1h = *(const short8*)&WFH[w1];
        short8 w1l = *(const short8*)&WFL[w1];
        for (int kt = 0; kt < 12; kt++) {
            short8 cah = ah, cal = al, cw0h = w0h, cw0l = w0l, cw1h = w1h, cw1l = w1l;
            if (kt < 11) {
                int ao = (kt + 1) * 512 + abase;
                size_t woff = (size_t)(kt + 1) * 512;
                ah = *(const short8*)&AH[ao];
                al = *(const short8*)&AL[ao];
                w0h = *(const short8*)&WFH[w0 + woff];
                w0l = *(const short8*)&WFL[w0 + woff];
                w1h = *(const short8*)&WFH[w1 + woff];
                w1l = *(const short8*)&WFL[w1 + woff];
            }
            acc0 = MFMA16(cah, cw0h, acc0);
            acc0 = MFMA16(cah, cw0l, acc0);
            acc0 = MFMA16(cal, cw0h, acc0);
            acc1v = MFMA16(cah, cw1h, acc1v);
            acc1v = MFMA16(cah, cw1l, acc1v);
            acc1v = MFMA16(cal, cw1h, acc1v);
        }
#pragma unroll
        for (int reg = 0; reg < 4; reg++) {
            int row = quad * 4 + reg;
            PRED[row * 128 + wav * 16 + l15] = acc0[reg];
            PRED[row * 128 + 64 + wav * 16 + l15] = acc1v[reg];
        }
    }
    __syncthreads();
    for (int i = tid; i < 2048; i += 256) {
        int r = i >> 7, c = i & 127;
        float v = PRED[i] + bias[c];
        float s = 1.f / (1.f + __expf(-v));
        size_t grow = ((size_t)(b * Nn + n0 + r)) * 64;
        if (c < 64) {
            z[grow + c] = s;
        } else {
            int c2 = c - 64;
            int fa = fragaddr(r, c2);
            float hv = bf2f(AH[fa]) + bf2f(AL[fa]);
            float hrv = hv * s;
            hr[grow + c2] = hrv;
            HRS[r * 64 + c2] = hrv;
        }
    }
    __syncthreads();
    for (int i = tid; i < 1024; i += 256) {
        int c = i >> 4, r = i & 15;
        float hrv = HRS[r * 64 + c];
        size_t gi = (size_t)b * 32768 + (size_t)c * 512 + n0 + r;
        ushort hi = f2bf(hrv);
        hrTh[gi] = hi;
        hrTl[gi] = f2bf(hrv - bf2f(hi));
    }
}

// stage2: ht = tanh(A@Wht + b); h = z*h + (1-z)*ht -> global fp32 + bf16 transposed
__global__ __launch_bounds__(256) void k_cell2(
        const float* __restrict__ hrp, const float* __restrict__ x,
        const float* __restrict__ t1x, const float* __restrict__ t2x,
        const ushort* __restrict__ AfH, const ushort* __restrict__ AfL,
        const ushort* __restrict__ hrTh, const ushort* __restrict__ hrTl,
        const ushort* __restrict__ WFH, const ushort* __restrict__ WFL,
        const float* __restrict__ bias,
        const float* __restrict__ z, float* __restrict__ h,
        ushort* __restrict__ hTh, ushort* __restrict__ hTl, int t) {
    __shared__ float lds[9216];
    ushort* AH = (ushort*)lds;
    ushort* AL = (ushort*)(lds + 3072);
    float* PRED = lds + 6144;
    float* HRS  = lds + 8192;
    int tid = threadIdx.x;
    int b = blockIdx.x >> 5;
    int rowblk = blockIdx.x & 31;
    int n0 = rowblk * 16;
    size_t hoff = ((size_t)b * Nn + n0) * 64;
    size_t xoff = ((size_t)(b * Tn + t) * Nn + n0) * 64;

    stage_segs(AH, AL, hrp + hoff, x, t1x, t2x, xoff, tid);
    phase_A16(AH, AL, hrTh + (size_t)b * 32768, hrTl + (size_t)b * 32768,
              AfH, AfL, rowblk, tid);
    __syncthreads();

    // phase B2: ht[16][64] = A[16][384] @ Wht — MFMA, 1 col-pass/wave
    int lane = tid & 63, wav = tid >> 6;
    int quad = lane >> 4, l15 = lane & 15;
    {
        int abase = quad * 128 + l15 * 8;
        size_t w0 = ((size_t)wav * 12) * 512 + lane * 8;
        f32x4 acc = {0.f,0.f,0.f,0.f};
        short8 ah = *(const short8*)&AH[abase];
        short8 al = *(const short8*)&AL[abase];
        short8 wh = *(const short8*)&WFH[w0];
        short8 wl = *(const short8*)&WFL[w0];
        for (int kt = 0; kt < 12; kt++) {
            short8 cah = ah, cal = al, cwh = wh, cwl = wl;
            if (kt < 11) {
                int ao = (kt + 1) * 512 + abase;
                size_t woff = (size_t)(kt + 1) * 512;
                ah = *(const short8*)&AH[ao];
                al = *(const short8*)&AL[ao];
                wh = *(const short8*)&WFH[w0 + woff];
                wl = *(const short8*)&WFL[w0 + woff];
            }
            acc = MFMA16(cah, cwh, acc);
            acc = MFMA16(cah, cwl, acc);
            acc = MFMA16(cal, cwh, acc);
        }
#pragma unroll
        for (int reg = 0; reg < 4; reg++)
            PRED[(quad * 4 + reg) * 64 + wav * 16 + l15] = acc[reg];
    }
    __syncthreads();
    for (int i = tid; i < 1024; i += 256) {
        int c = i & 63;
        float ht = tanhf(PRED[i] + bias[c]);
        size_t p = ((size_t)(b * Nn + n0 + (i >> 6))) * 64 + c;
        float zz = z[p], hold = h[p];
        float hn = zz * hold + (1.f - zz) * ht;
        h[p] = hn;
        HRS[i] = hn;
    }
    __syncthreads();
    for (int i = tid; i < 1024; i += 256) {
        int c = i >> 4, r = i & 15;
        float hn = HRS[r * 64 + c];
        size_t gi = (size_t)b * 32768 + (size_t)c * 512 + n0 + r;
        ushort hi = f2bf(hn);
        hTh[gi] = hi;
        hTl[gi] = f2bf(hn - bf2f(hi));
    }
}

// ---------------- projections ----------------
__global__ __launch_bounds__(256) void k_proj(
        const float* __restrict__ h, const float* __restrict__ W1cat,
        const float* __restrict__ b1,
        float* __restrict__ sproj, float* __restrict__ tproj) {
    __shared__ float As[16][33];
    __shared__ float Ws[16 * 128];
    int tid = threadIdx.x;
    int row0 = blockIdx.x * 32;
    const float* hp = h + (size_t)row0 * 64;
    float acc[2][8] = {};
    int tx = tid & 15, ty = tid >> 4;
    int lr = tid >> 3;
    int lk = (tid & 7) * 2;
    int wk = tid >> 4;
    int wc = (tid & 15) * 8;
    for (int kt = 0; kt < 4; kt++) {
        int c0 = kt * 16;
        float2 a2 = *(const float2*)&hp[lr * 64 + c0 + lk];
        const float4* wsrc = (const float4*)&W1cat[(size_t)(kt * 16 + wk) * 128 + wc];
        float4 w0 = wsrc[0], w1 = wsrc[1];
        As[lk][lr] = a2.x;
        As[lk + 1][lr] = a2.y;
        *(float4*)&Ws[wk * 128 + wc] = w0;
        *(float4*)&Ws[wk * 128 + wc + 4] = w1;
        __syncthreads();
#pragma unroll
        for (int kk = 0; kk < 16; kk++) {
            float a0 = As[kk][ty * 2 + 0];
            float a1 = As[kk][ty * 2 + 1];
            float4 p0 = *(const float4*)&Ws[kk * 128 + tx * 8];
            float4 p1 = *(const float4*)&Ws[kk * 128 + tx * 8 + 4];
            float w[8] = { p0.x, p0.y, p0.z, p0.w, p1.x, p1.y, p1.z, p1.w };
#pragma unroll
            for (int cc = 0; cc < 8; cc++) {
                acc[0][cc] += a0 * w[cc];
                acc[1][cc] += a1 * w[cc];
            }
        }
        __syncthreads();
    }
#pragma unroll
    for (int rr = 0; rr < 2; rr++) {
        int row = row0 + ty * 2 + rr;
#pragma unroll
        for (int cc = 0; cc < 8; cc++) {
            int col = tx * 8 + cc;
            float v = acc[rr][cc];
            if (col < 64) sproj[(size_t)row * 64 + col] = v + b1[col];
            else tproj[(size_t)row * 64 + (col - 64)] = v;
        }
    }
}

// ---------------- logits ----------------
__global__ __launch_bounds__(256) void k_logits(
        const float* __restrict__ sproj, const float* __restrict__ tproj,
        const float* __restrict__ W2, const float* __restrict__ b2,
        float* __restrict__ out) {
    __shared__ float sp[32 * 64];
    __shared__ float tp[64 * 65];
    __shared__ float w2s[64];
    int tid = threadIdx.x;
    int bb = blockIdx.x >> 7;
    int st = (blockIdx.x >> 3) & 15;
    int tt = blockIdx.x & 7;
    const float* spg = sproj + ((size_t)bb * Nn + st * 32) * 64;
    const float* tpg = tproj + ((size_t)bb * Nn + tt * 64) * 64;
    for (int i = tid; i < 2048; i += 256) sp[i] = spg[i];
    for (int i = tid; i < 4096; i += 256) {
        int tl = i >> 6, hh = i & 63;
        tp[tl * 65 + hh] = tpg[i];
    }
    if (tid < 64) w2s[tid] = W2[tid];
    __syncthreads();
    float bias = *b2;
    int tl = tid & 63, sg = tid >> 6;
    for (int si = 0; si < 8; si++) {
        int s = sg * 8 + si;
        float acc = bias;
#pragma unroll 8
        for (int hh = 0; hh < 64; hh++) {
            float v = sp[s * 64 + hh] + tp[tl * 65 + hh];
            acc += fmaxf(v, 0.f) * w2s[hh];
        }
        out[(size_t)bb * Nn * Nn + (size_t)(st * 32 + s) * Nn + tt * 64 + tl] = acc;
    }
}

// ---------------- host ----------------
extern "C" void kernel_launch(void* const* d_in, const int* in_sizes, int n_in,
                              void* d_out, int out_size, void* d_ws, size_t ws_size,
                              hipStream_t stream) {
    const float* x  = (const float*)d_in[0];
    const float* ew = (const float*)d_in[1];
    const float* Wx = (const float*)d_in[2];
    const float* bx = (const float*)d_in[3];
    const float* Wh = (const float*)d_in[4];
    const float* bh = (const float*)d_in[5];
    const float* W1 = (const float*)d_in[6];
    const float* b1 = (const float*)d_in[7];
    const float* W2 = (const float*)d_in[8];
    const float* b2 = (const float*)d_in[9];
    const int* ei   = (const int*)d_in[10];
    const int* esrc = ei;
    const int* edst = ei + En;

    float* ws = (float*)d_ws;
    float* deg   = ws + OFF_DEG;
    float* dinv  = ws + OFF_DINV;
    float* L1d   = ws + OFF_L1D;
    float* L2d   = ws + OFF_L2D;
    float* WzrC  = ws + OFF_WZR;
    float* WhC   = ws + OFF_WHT;
    float* bzr   = ws + OFF_BZR;
    float* bht   = ws + OFF_BHT;
    float* W1cat = ws + OFF_W1C;
    float* T1x   = ws + OFF_T1X;
    float* T2x   = ws + OFF_T2X;
    float* h     = ws + OFF_H;
    float* z     = ws + OFF_Z;
    float* hr    = ws + OFF_HR;
    float* sproj = ws + OFF_SP;
    float* tproj = ws + OFF_TP;
    ushort* AfH  = (ushort*)(ws + OFF_LFH);
    ushort* AfL  = (ushort*)(ws + OFF_LFL);
    ushort* hTh  = (ushort*)(ws + OFF_HTH);
    ushort* hTl  = (ushort*)(ws + OFF_HTL);
    ushort* hrTh = (ushort*)(ws + OFF_HRTH);
    ushort* hrTl = (ushort*)(ws + OFF_HRTL);
    // W-fragments alias the sproj region (dead until k_proj, which runs after recurrence)
    ushort* WzFH = (ushort*)(ws + OFF_SP);
    ushort* WzFL = WzFH + 98304;
    ushort* WhFH = WzFL + 98304;
    ushort* WhFL = WhFH + 49152;
    float* out   = (float*)d_out;

    hipMemsetAsync(deg, 0, 512 * sizeof(float), stream);
    hipMemsetAsync(L1d, 0, (size_t)Nn * Nn * sizeof(float), stream);
    hipMemsetAsync(h, 0, (size_t)Bn * NC * sizeof(float), stream);
    hipMemsetAsync(hTh, 0, 262144 * sizeof(ushort), stream);
    hipMemsetAsync(hTl, 0, 262144 * sizeof(ushort), stream);

    k_deg<<<64, 256, 0, stream>>>(ew, esrc, deg);
    k_dinv<<<2, 256, 0, stream>>>(deg, dinv);
    k_nwdense<<<64, 256, 0, stream>>>(ew, esrc, edst, dinv, L1d);
    k_l2<<<64, 256, 0, stream>>>(L1d, L2d);
    k_lfrag<<<2048, 256, 0, stream>>>(L1d, L2d, AfH, AfL);
    k_repack<<<(156032 + 255) / 256, 256, 0, stream>>>(Wx, bx, Wh, bh, W1,
                                                       WzrC, WhC, bzr, bht, W1cat);
    k_wfrag<<<(147456 + 255) / 256, 256, 0, stream>>>(WzrC, WhC, WzFH, WzFL, WhFH, WhFL);

    k_lmm2<<<Bn * Tn * 8, 256, 0, stream>>>(L1d, L2d, x, T1x, T2x);

    for (int t = 0; t < Tn; t++) {
        for (int l = 0; l < Ln; l++) {
            k_cell1<<<256, 256, 0, stream>>>(h, x, T1x, T2x, AfH, AfL, hTh, hTl,
                                             WzFH + (size_t)l * 49152,
                                             WzFL + (size_t)l * 49152,
                                             bzr + l * 128, z, hr, hrTh, hrTl, t);
            k_cell2<<<256, 256, 0, stream>>>(hr, x, T1x, T2x, AfH, AfL, hrTh, hrTl,
                                             WhFH + (size_t)l * 24576,
                                             WhFL + (size_t)l * 24576,
                                             bht + l * 64, z, h, hTh, hTl, t);
        }
    }

    k_proj<<<128, 256, 0, stream>>>(h, W1cat, b1, sproj, tproj);
    k_logits<<<Bn * 16 * 8, 256, 0, stream>>>(sproj, tproj, W2, b2, out);
}